// Round 5
// baseline (433.229 us; speedup 1.0000x reference)
//
#include <hip/hip_runtime.h>
#include <stdint.h>

#define N_BATCH 128
#define C_IN    156
#define T_SMP   156
#define H_HID   1024
#define O_OUT   20

// Baked permutation (from reference _top_down construction)
__constant__ int PERM_C[156] = {
  20,21,48,49,68,69,6,7,34,35,58,59,12,13,2,3,38,39,72,73,56,57,22,23,16,17,
  64,65,44,45,30,31,0,1,10,11,28,29,40,41,52,53,66,67,76,77,46,47,32,33,18,19,
  60,61,74,75,54,55,26,27,4,5,42,43,62,63,14,15,36,37,70,71,8,9,24,25,50,51,
  98,99,126,127,146,147,84,85,112,113,136,137,90,91,80,81,116,117,150,151,134,135,
  100,101,94,95,142,143,122,123,108,109,78,79,88,89,106,107,118,119,130,131,144,145,
  154,155,124,125,110,111,96,97,138,139,152,153,132,133,104,105,82,83,120,121,
  140,141,92,93,114,115,148,149,86,87,102,103,128,129
};

// ref_next[d] = REF_KERNEL[d+1] = -20*(d+1)*exp(-d), correctly-rounded fp32
__device__ __constant__ float REFN_C[15] = {
  -20.0f,
  -14.7151776468576930f,
  -8.1201169941967630f,
  -3.9829654694291155f,
  -1.8315638888734178f,
  -0.80855363989025606f,
  -0.34702530473329017f,
  -0.14590111448872258f,
  -0.060383273022452135f,
  -0.024681960817335913f,
  -0.0099879845477466679f,
  -0.0040084081896589585f,
  -0.0015974952118653345f,
  -0.00063348115597555236f,
  -0.00024945861573107036f
};

#define IIR_A  0.904837418035959573   // exp(-1/10)
#define IIR_CK 0.271828182845904524   // e/10

// ---------------------------------------------------------------------------
// K1: build packed active-index lists for both paths.
// ---------------------------------------------------------------------------
__global__ void __launch_bounds__(256) k_build_lists(
    const float* __restrict__ x,
    uint32_t* __restrict__ lists_m, uint32_t* __restrict__ cnt_m,
    uint32_t* __restrict__ lists_l, uint32_t* __restrict__ cnt_l)
{
  extern __shared__ float xl[];            // [156*156]
  const int n = blockIdx.x;
  const float* xn = x + n * (C_IN * T_SMP);
  for (int i = threadIdx.x; i < C_IN * T_SMP; i += 256) xl[i] = xn[i];
  __syncthreads();
  const int t = threadIdx.x;
  if (t < T_SMP) {
    { // main path
      uint32_t* Lp = lists_m + (n * T_SMP + t) * 40;
      uint32_t w = 0; int cnt = 0, nw = 0;
      for (int c = 0; c < C_IN; ++c) {
        if (xl[c * T_SMP + t] > 0.5f) {
          w |= ((uint32_t)c) << ((cnt & 3) * 8);
          ++cnt;
          if ((cnt & 3) == 0) { Lp[nw++] = w; w = 0; }
        }
      }
      if (cnt & 3) {
        for (int k = cnt & 3; k < 4; ++k) w |= 156u << (k * 8);
        Lp[nw++] = w;
      }
      cnt_m[n * T_SMP + t] = (uint32_t)nw;
    }
    { // location path
      uint32_t* Lp = lists_l + (n * T_SMP + t) * 40;
      const int pc = PERM_C[t];
      uint32_t w = 0; int cnt = 0, nw = 0;
      for (int tau = 0; tau < T_SMP; ++tau) {
        if (xl[pc * T_SMP + tau] > 0.5f) {
          w |= ((uint32_t)tau) << ((cnt & 3) * 8);
          ++cnt;
          if ((cnt & 3) == 0) { Lp[nw++] = w; w = 0; }
        }
      }
      if (cnt & 3) {
        for (int k = cnt & 3; k < 4; ++k) w |= 156u << (k * 8);
        Lp[nw++] = w;
      }
      cnt_l[n * T_SMP + t] = (uint32_t)nw;
    }
  }
}

// ---------------------------------------------------------------------------
// K2 v5: fused layer-1 with EXACT int64 fixed-point accumulation.
// LDS table wQ[c*64+lane] = llrint(w[h0+lane][c] * 2^50)  (i64, 78.5KiB).
// Per active channel: ds_read_b64 + v_add_co/addc (full-rate int) -- no fp64
// cvt/add in the inner loop. Sum is EXACT in int64 (order-independent);
// upre = (double)acc * 2^-50 once per t (error ~1e-14, same order as f64
// rounding discrepancy vs the np reference that we already pass with).
// 2 blocks/CU (157KiB), block = 4 waves = 4 batches. Grid (16 hc,32 ng,2 p).
// ---------------------------------------------------------------------------
__global__ void __launch_bounds__(256, 2) k_layer1(
    const float* __restrict__ w_fc1, const float* __restrict__ w_loc1,
    const uint32_t* __restrict__ lists_m, const uint32_t* __restrict__ cnt_m,
    const uint32_t* __restrict__ lists_l, const uint32_t* __restrict__ cnt_l,
    uint64_t* __restrict__ s1m_m, uint64_t* __restrict__ s1m_l)
{
  extern __shared__ long long wQ[];        // [157][64]
  const int hc   = blockIdx.x;             // 0..15 (h chunk of 64)
  const int n0   = blockIdx.y * 4;
  const int path = blockIdx.z;
  const int tid  = threadIdx.x;
  const float* w = (path == 0) ? w_fc1 : w_loc1;
  const uint32_t* lists = (path == 0) ? lists_m : lists_l;
  const uint32_t* cnts  = (path == 0) ? cnt_m  : cnt_l;
  uint64_t* s1m = (path == 0) ? s1m_m : s1m_l;
  const int h0 = hc * 64;

  { // stage: thread tid owns h-row hp = tid&63, c-quarter = tid>>6 (39 c each)
    const int hp = tid & 63;
    const int c0 = (tid >> 6) * 39;
    const float* wr = w + (size_t)(h0 + hp) * C_IN + c0;
    #pragma unroll
    for (int k = 0; k < 39; ++k) {
      double wd = (double)wr[k] * 0x1p50;
      wQ[(c0 + k) * 64 + hp] = __double2ll_rn(wd);
    }
    if (tid < 64) wQ[156 * 64 + tid] = 0;  // guard row (padded index 156)
  }
  __syncthreads();

  const int wv   = tid >> 6;               // wave -> batch offset
  const int lane = tid & 63;
  const int n    = n0 + wv;
  const int rbase = n * T_SMP;

  float pend[15];
  #pragma unroll
  for (int d = 0; d < 15; ++d) pend[d] = 0.0f;
  double e1 = 0.0, e2 = 0.0;

  // prefetch t=0 list
  int nw = (int)cnts[rbase];
  uint4 pkA = *(const uint4*)(lists + (size_t)rbase * 40);
  uint4 pkB = *(const uint4*)(lists + (size_t)rbase * 40 + 4);

  for (int t = 0; t < T_SMP; ++t) {
    const int base = rbase + t;
    const int basen = (t < T_SMP - 1) ? base + 1 : base;
    const int nw_n = (int)cnts[basen];
    const uint4 pkA_n = *(const uint4*)(lists + (size_t)basen * 40);
    const uint4 pkB_n = *(const uint4*)(lists + (size_t)basen * 40 + 4);

    long long a0 = 0, a1 = 0;

#define DOWORD(PK) do {                                                      \
    uint32_t pk_ = __builtin_amdgcn_readfirstlane(PK);                       \
    int c0_ = pk_ & 255, c1_ = (pk_ >> 8) & 255,                             \
        c2_ = (pk_ >> 16) & 255, c3_ = pk_ >> 24;                            \
    long long F0 = wQ[c0_ * 64 + lane];                                      \
    long long F1 = wQ[c1_ * 64 + lane];                                      \
    long long F2 = wQ[c2_ * 64 + lane];                                      \
    long long F3 = wQ[c3_ * 64 + lane];                                      \
    a0 += F0 + F2;                                                           \
    a1 += F1 + F3;                                                           \
  } while (0)

    if (nw > 0) DOWORD(pkA.x);
    if (nw > 1) DOWORD(pkA.y);
    if (nw > 2) DOWORD(pkA.z);
    if (nw > 3) DOWORD(pkA.w);
    if (nw > 4) DOWORD(pkB.x);
    if (nw > 5) DOWORD(pkB.y);
    if (nw > 6) DOWORD(pkB.z);
    if (nw > 7) DOWORD(pkB.w);
    if (nw > 8) {   // rare tail (>32 active channels)
      const uint32_t* Lp = lists + (size_t)base * 40;
      for (int wi = 8; wi < nw; ++wi) DOWORD(Lp[wi]);
    }
#undef DOWORD

    double upre = (double)(a0 + a1) * 0x1p-50;
    e1 = IIR_A * e1 + upre;
    e2 = IIR_A * e2 + e1;
    float uf = (float)(IIR_CK * (e2 - e1));
    float um = uf + pend[0];
    bool sp = (um >= 10.0f);
    float s = sp ? 1.0f : 0.0f;
    #pragma unroll
    for (int d = 0; d < 14; ++d) pend[d] = fmaf(s, REFN_C[d], pend[d + 1]);
    pend[14] = s * REFN_C[14];
    uint64_t bal = __ballot(sp);
    if (lane == 0) s1m[(size_t)base * 16 + hc] = bal;

    nw = nw_n; pkA = pkA_n; pkB = pkB_n;
  }
}

// ---------------------------------------------------------------------------
// K3 v5: layer-2 dense via bitmask, int32-table (scale 2^31) + int64 accum.
// Per spike-bit: 5 x (ds_read_b32 + sext + add64) -- no fp64 in loop.
// Grid: (128 n x 4 t-chunks, 2 path); lane = (hw=lane>>2 word, og=lane&3).
// ---------------------------------------------------------------------------
__global__ void __launch_bounds__(512, 1) k_layer2(
    const float* __restrict__ w_fc2, const float* __restrict__ w_loc2,
    const uint64_t* __restrict__ s1m_m, const uint64_t* __restrict__ s1m_l,
    float* __restrict__ u2_m, float* __restrict__ u2_l)
{
  extern __shared__ int w2Q[];             // [1024][20] i32, scale 2^31
  const int path = blockIdx.y;
  const int n  = blockIdx.x >> 2;
  const int tc = blockIdx.x & 3;
  const float* w2 = (path == 0) ? w_fc2 : w_loc2;
  const uint64_t* s1m = (path == 0) ? s1m_m : s1m_l;
  float* u2 = (path == 0) ? u2_m : u2_l;
  for (int i = threadIdx.x; i < O_OUT * H_HID; i += 512) {
    int o = i / H_HID, h = i % H_HID;
    w2Q[h * O_OUT + o] = __double2int_rn((double)w2[i] * 0x1p31);
  }
  __syncthreads();
  const int wv   = threadIdx.x >> 6;
  const int lane = threadIdx.x & 63;
  const int hw = lane >> 2, og = lane & 3;

  for (int tt = wv; tt < 39; tt += 8) {
    const int t = tc * 39 + tt;
    const int id = n * T_SMP + t;
    uint64_t m = s1m[(size_t)id * 16 + hw];
    long long acc0 = 0, acc1 = 0, acc2 = 0, acc3 = 0, acc4 = 0;
    while (m) {
      int b = __builtin_ctzll(m);
      m &= m - 1;
      const int* wp = &w2Q[(hw * 64 + b) * O_OUT + og];
      acc0 += wp[0];
      acc1 += wp[4];
      acc2 += wp[8];
      acc3 += wp[12];
      acc4 += wp[16];
    }
    #pragma unroll
    for (int off = 4; off <= 32; off <<= 1) {
      acc0 += __shfl_xor(acc0, off);
      acc1 += __shfl_xor(acc1, off);
      acc2 += __shfl_xor(acc2, off);
      acc3 += __shfl_xor(acc3, off);
      acc4 += __shfl_xor(acc4, off);
    }
    if (lane < 4) {
      u2[((size_t)n * O_OUT + og +  0) * T_SMP + t] = (float)((double)acc0 * 0x1p-31);
      u2[((size_t)n * O_OUT + og +  4) * T_SMP + t] = (float)((double)acc1 * 0x1p-31);
      u2[((size_t)n * O_OUT + og +  8) * T_SMP + t] = (float)((double)acc2 * 0x1p-31);
      u2[((size_t)n * O_OUT + og + 12) * T_SMP + t] = (float)((double)acc3 * 0x1p-31);
      u2[((size_t)n * O_OUT + og + 16) * T_SMP + t] = (float)((double)acc4 * 0x1p-31);
    }
  }
}

// ---------------------------------------------------------------------------
// K4: layer-2 psp (fp64 IIR) + spike scan, write concatenated output.
// ---------------------------------------------------------------------------
__global__ void __launch_bounds__(256) k_psp_spike_out(
    const float* __restrict__ u2_m, const float* __restrict__ u2_l,
    float* __restrict__ out)
{
  const int rid = blockIdx.x * 256 + threadIdx.x;   // 0..5119
  const int p = rid / (N_BATCH * O_OUT);
  const int r = rid % (N_BATCH * O_OUT);            // n*20+o
  const float* base = ((p == 0) ? u2_m : u2_l) + (size_t)r * T_SMP;
  float* ob = out + (size_t)r * (2 * T_SMP) + p * T_SMP;
  float pend[15];
  #pragma unroll
  for (int d = 0; d < 15; ++d) pend[d] = 0.0f;
  double e1 = 0.0, e2 = 0.0;
  for (int t = 0; t < T_SMP; ++t) {
    double xv = (double)base[t];
    e1 = IIR_A * e1 + xv;
    e2 = IIR_A * e2 + e1;
    float uf = (float)(IIR_CK * (e2 - e1));
    float um = uf + pend[0];
    float s  = (um >= 10.0f) ? 1.0f : 0.0f;
    #pragma unroll
    for (int d = 0; d < 14; ++d) pend[d] = fmaf(s, REFN_C[d], pend[d + 1]);
    pend[14] = s * REFN_C[14];
    ob[t] = s;
  }
}

// ---------------------------------------------------------------------------
extern "C" void kernel_launch(void* const* d_in, const int* in_sizes, int n_in,
                              void* d_out, int out_size, void* d_ws, size_t ws_size,
                              hipStream_t stream) {
  const float* x      = (const float*)d_in[0];
  const float* w_fc1  = (const float*)d_in[1];
  const float* w_fc2  = (const float*)d_in[2];
  const float* w_loc1 = (const float*)d_in[3];
  const float* w_loc2 = (const float*)d_in[4];
  float* out = (float*)d_out;
  char* ws = (char*)d_ws;

  // workspace layout
  uint32_t* lists_m = (uint32_t*)(ws + 0);          //  3,194,880
  uint32_t* lists_l = (uint32_t*)(ws + 3194880);    //  3,194,880
  uint32_t* cnt_m   = (uint32_t*)(ws + 6389760);    //     79,872
  uint32_t* cnt_l   = (uint32_t*)(ws + 6469632);    //     79,872
  uint64_t* s1m_m   = (uint64_t*)(ws + 6549504);    //  2,555,904
  uint64_t* s1m_l   = (uint64_t*)(ws + 9105408);    //  2,555,904
  float*    u2_m    = (float*)   (ws + 11661312);   //  1,597,440
  float*    u2_l    = (float*)   (ws + 13258752);   //  1,597,440

  hipLaunchKernelGGL(k_build_lists, dim3(128), dim3(256),
                     C_IN * T_SMP * sizeof(float), stream,
                     x, lists_m, cnt_m, lists_l, cnt_l);
  hipLaunchKernelGGL(k_layer1, dim3(16, 32, 2), dim3(256),
                     157 * 64 * sizeof(long long), stream,
                     w_fc1, w_loc1, lists_m, cnt_m, lists_l, cnt_l, s1m_m, s1m_l);
  hipLaunchKernelGGL(k_layer2, dim3(512, 2), dim3(512),
                     H_HID * O_OUT * sizeof(int), stream,
                     w_fc2, w_loc2, s1m_m, s1m_l, u2_m, u2_l);
  hipLaunchKernelGGL(k_psp_spike_out, dim3(20), dim3(256), 0, stream,
                     u2_m, u2_l, out);
}

// Round 6
// 370.239 us; speedup vs baseline: 1.1701x; 1.1701x over previous
//
#include <hip/hip_runtime.h>
#include <stdint.h>

#define N_BATCH 128
#define C_IN    156
#define T_SMP   156
#define H_HID   1024
#define O_OUT   20

// Baked permutation (from reference _top_down construction)
__constant__ int PERM_C[156] = {
  20,21,48,49,68,69,6,7,34,35,58,59,12,13,2,3,38,39,72,73,56,57,22,23,16,17,
  64,65,44,45,30,31,0,1,10,11,28,29,40,41,52,53,66,67,76,77,46,47,32,33,18,19,
  60,61,74,75,54,55,26,27,4,5,42,43,62,63,14,15,36,37,70,71,8,9,24,25,50,51,
  98,99,126,127,146,147,84,85,112,113,136,137,90,91,80,81,116,117,150,151,134,135,
  100,101,94,95,142,143,122,123,108,109,78,79,88,89,106,107,118,119,130,131,144,145,
  154,155,124,125,110,111,96,97,138,139,152,153,132,133,104,105,82,83,120,121,
  140,141,92,93,114,115,148,149,86,87,102,103,128,129
};

// ref_next[d] = REF_KERNEL[d+1] = -20*(d+1)*exp(-d), correctly-rounded fp32
__device__ __constant__ float REFN_C[15] = {
  -20.0f,
  -14.7151776468576930f,
  -8.1201169941967630f,
  -3.9829654694291155f,
  -1.8315638888734178f,
  -0.80855363989025606f,
  -0.34702530473329017f,
  -0.14590111448872258f,
  -0.060383273022452135f,
  -0.024681960817335913f,
  -0.0099879845477466679f,
  -0.0040084081896589585f,
  -0.0015974952118653345f,
  -0.00063348115597555236f,
  -0.00024945861573107036f
};

#define IIR_A  0.904837418035959573   // exp(-1/10)
#define IIR_CK 0.271828182845904524   // e/10

// ---------------------------------------------------------------------------
// K1 v2: build 156-bit activity masks via ballot.
// xm_m[(n*156+t)*4 + j] : bits over channel c (j=0: c 0..63, j=1: 64..127,
//                          j=2: 128..155) of x[n,c,t] != 0.
// xm_l[(n*156+j)*4 + k] : bits over tau of x[n, PERM[j], tau].
// Block per n, 4 waves cover t/j strided.
// ---------------------------------------------------------------------------
__global__ void __launch_bounds__(256, 1) k_masks(
    const float* __restrict__ x,
    uint64_t* __restrict__ xm_m, uint64_t* __restrict__ xm_l)
{
  extern __shared__ float xl[];            // [156*156]
  const int n = blockIdx.x;
  const float* xn = x + n * (C_IN * T_SMP);
  for (int i = threadIdx.x; i < C_IN * T_SMP; i += 256) xl[i] = xn[i];
  __syncthreads();
  const int wv = threadIdx.x >> 6, lane = threadIdx.x & 63;
  for (int t = wv; t < T_SMP; t += 4) {
    { // main path: bits over c at column t
      float v0 = xl[lane * T_SMP + t];
      float v1 = xl[(lane + 64) * T_SMP + t];
      float v2 = (lane < 28) ? xl[(lane + 128) * T_SMP + t] : 0.0f;
      uint64_t m0 = __ballot(v0 > 0.5f);
      uint64_t m1 = __ballot(v1 > 0.5f);
      uint64_t m2 = __ballot(v2 > 0.5f);
      if (lane == 0) {
        uint64_t* p = xm_m + ((size_t)n * T_SMP + t) * 4;
        p[0] = m0; p[1] = m1; p[2] = m2;
      }
    }
    { // location path: bits over tau at channel PERM[t]
      const int pc = PERM_C[t];
      float v0 = xl[pc * T_SMP + lane];
      float v1 = xl[pc * T_SMP + lane + 64];
      float v2 = (lane < 28) ? xl[pc * T_SMP + lane + 128] : 0.0f;
      uint64_t m0 = __ballot(v0 > 0.5f);
      uint64_t m1 = __ballot(v1 > 0.5f);
      uint64_t m2 = __ballot(v2 > 0.5f);
      if (lane == 0) {
        uint64_t* p = xm_l + ((size_t)n * T_SMP + t) * 4;
        p[0] = m0; p[1] = m1; p[2] = m2;
      }
    }
  }
}

// ---------------------------------------------------------------------------
// K2 v6: fused layer-1. Biased-u32 fixed-point table, mask-driven gather.
// wB[c*64+lane] = round(w[h0+lane][c]*2^28) + 2^31  (u32, 39KB LDS,
// conflict-free, 4 blocks/CU = 16 waves/CU).
// Per active channel: 1 VALU addr add + ds_read_b32 + add_co/addc = ~3 VALU.
// Index extraction: ctz loop on wave-uniform (readfirstlane'd) mask halves
// -> SALU pipe. Sum exact in u64; Sw = acc - K*2^31 (K = popcount, SALU).
// upre = (double)Sw * 2^-28 (table quant ~2e-9/term, same order as the
// 2^-31 layer-2 table that already passes with absmax 0).
// Block = 4 waves = 4 batches. Grid (16 hc, 32 ng, 2 path).
// ---------------------------------------------------------------------------
__global__ void __launch_bounds__(256, 4) k_layer1(
    const float* __restrict__ w_fc1, const float* __restrict__ w_loc1,
    const uint64_t* __restrict__ xm_m, const uint64_t* __restrict__ xm_l,
    uint64_t* __restrict__ s1m_m, uint64_t* __restrict__ s1m_l)
{
  __shared__ uint32_t wB[C_IN * 64];       // [156][64]
  const int hc   = blockIdx.x;             // 0..15 (h chunk of 64)
  const int n0   = blockIdx.y * 4;
  const int path = blockIdx.z;
  const int tid  = threadIdx.x;
  const float* w = (path == 0) ? w_fc1 : w_loc1;
  const uint64_t* xm = (path == 0) ? xm_m : xm_l;
  uint64_t* s1m = (path == 0) ? s1m_m : s1m_l;
  const int h0 = hc * 64;

  { // stage: thread tid owns h-row hp = tid&63, c-quarter = tid>>6 (39 c each)
    const int hp = tid & 63;
    const int c0 = (tid >> 6) * 39;
    const float* wr = w + (size_t)(h0 + hp) * C_IN + c0;
    #pragma unroll
    for (int k = 0; k < 39; ++k) {
      int q = __double2int_rn((double)wr[k] * 0x1p28);
      wB[(c0 + k) * 64 + hp] = (uint32_t)q + 0x80000000u;
    }
  }
  __syncthreads();

  const int wv   = tid >> 6;               // wave -> batch offset
  const int lane = tid & 63;
  const int n    = n0 + wv;
  const int rbase = n * T_SMP;

  float pend[15];
  #pragma unroll
  for (int d = 0; d < 15; ++d) pend[d] = 0.0f;
  double e1 = 0.0, e2 = 0.0;

  // prefetch t=0 masks
  const uint64_t* mp0 = xm + (size_t)rbase * 4;
  ulonglong2 mA = *(const ulonglong2*)mp0;
  uint64_t   mC = mp0[2];

  for (int t = 0; t < T_SMP; ++t) {
    const int base = rbase + t;
    const int basen = (t < T_SMP - 1) ? base + 1 : base;
    const uint64_t* mpn = xm + (size_t)basen * 4;
    const ulonglong2 mA_n = *(const ulonglong2*)mpn;
    const uint64_t   mC_n = mpn[2];

    // split into wave-uniform 32-bit halves (SGPR-resident)
    uint32_t l0 = __builtin_amdgcn_readfirstlane((uint32_t)mA.x);
    uint32_t h0_ = __builtin_amdgcn_readfirstlane((uint32_t)(mA.x >> 32));
    uint32_t l1 = __builtin_amdgcn_readfirstlane((uint32_t)mA.y);
    uint32_t h1_ = __builtin_amdgcn_readfirstlane((uint32_t)(mA.y >> 32));
    uint32_t l2 = __builtin_amdgcn_readfirstlane((uint32_t)mC);
    int K = __popc(l0) + __popc(h0_) + __popc(l1) + __popc(h1_) + __popc(l2);

    uint64_t acc = 0;
#define PROC(MW, CB) do {                                                    \
    uint32_t mw_ = (MW);                                                     \
    while (mw_) {                                                            \
      int b_ = __builtin_ctz(mw_);                                           \
      mw_ &= mw_ - 1;                                                        \
      acc += (uint64_t)wB[((CB) + b_) * 64 + lane];                          \
    }                                                                        \
  } while (0)
    PROC(l0, 0);
    PROC(h0_, 32);
    PROC(l1, 64);
    PROC(h1_, 96);
    PROC(l2, 128);
#undef PROC

    double upre = (double)(long long)(acc - ((uint64_t)K << 31)) * 0x1p-28;
    e1 = IIR_A * e1 + upre;
    e2 = IIR_A * e2 + e1;
    float uf = (float)(IIR_CK * (e2 - e1));
    float um = uf + pend[0];
    bool sp = (um >= 10.0f);
    float s = sp ? 1.0f : 0.0f;
    #pragma unroll
    for (int d = 0; d < 14; ++d) pend[d] = fmaf(s, REFN_C[d], pend[d + 1]);
    pend[14] = s * REFN_C[14];
    uint64_t bal = __ballot(sp);
    if (lane == 0) s1m[(size_t)base * 16 + hc] = bal;

    mA = mA_n; mC = mC_n;
  }
}

// ---------------------------------------------------------------------------
// K3 v6: layer-2 dense via bitmask, int32 table (scale 2^31) + i64 accum.
// ONE block per (n,path): stage w2Q once, 8 waves cover all 156 t.
// Lane = (hw = lane>>2 word, og = lane&3 o-group); butterfly over hw axis.
// u2 stored t-major: u2[t*2560 + n*20 + o] so K4 reads coalesce.
// ---------------------------------------------------------------------------
__global__ void __launch_bounds__(512, 1) k_layer2(
    const float* __restrict__ w_fc2, const float* __restrict__ w_loc2,
    const uint64_t* __restrict__ s1m_m, const uint64_t* __restrict__ s1m_l,
    float* __restrict__ u2_m, float* __restrict__ u2_l)
{
  extern __shared__ int w2Q[];             // [1024][20] i32, scale 2^31
  const int path = blockIdx.y;
  const int n = blockIdx.x;
  const float* w2 = (path == 0) ? w_fc2 : w_loc2;
  const uint64_t* s1m = (path == 0) ? s1m_m : s1m_l;
  float* u2 = (path == 0) ? u2_m : u2_l;
  for (int i = threadIdx.x; i < O_OUT * H_HID; i += 512) {
    int o = i / H_HID, h = i % H_HID;
    w2Q[h * O_OUT + o] = __double2int_rn((double)w2[i] * 0x1p31);
  }
  __syncthreads();
  const int wv   = threadIdx.x >> 6;
  const int lane = threadIdx.x & 63;
  const int hw = lane >> 2, og = lane & 3;

  for (int t = wv; t < T_SMP; t += 8) {
    const int id = n * T_SMP + t;
    uint64_t m = s1m[(size_t)id * 16 + hw];
    long long acc0 = 0, acc1 = 0, acc2 = 0, acc3 = 0, acc4 = 0;
    while (m) {
      int b = __builtin_ctzll(m);
      m &= m - 1;
      const int* wp = &w2Q[(hw * 64 + b) * O_OUT + og];
      acc0 += wp[0];
      acc1 += wp[4];
      acc2 += wp[8];
      acc3 += wp[12];
      acc4 += wp[16];
    }
    #pragma unroll
    for (int off = 4; off <= 32; off <<= 1) {
      acc0 += __shfl_xor(acc0, off);
      acc1 += __shfl_xor(acc1, off);
      acc2 += __shfl_xor(acc2, off);
      acc3 += __shfl_xor(acc3, off);
      acc4 += __shfl_xor(acc4, off);
    }
    if (lane < 4) {
      float* ub = u2 + (size_t)t * (N_BATCH * O_OUT) + n * O_OUT + og;
      ub[0]  = (float)((double)acc0 * 0x1p-31);
      ub[4]  = (float)((double)acc1 * 0x1p-31);
      ub[8]  = (float)((double)acc2 * 0x1p-31);
      ub[12] = (float)((double)acc3 * 0x1p-31);
      ub[16] = (float)((double)acc4 * 0x1p-31);
    }
  }
}

// ---------------------------------------------------------------------------
// K4: layer-2 psp (fp64 IIR) + spike scan, write concatenated output.
// u2 is t-major -> per-t loads are coalesced across the 5120 threads.
// ---------------------------------------------------------------------------
__global__ void __launch_bounds__(256) k_psp_spike_out(
    const float* __restrict__ u2_m, const float* __restrict__ u2_l,
    float* __restrict__ out)
{
  const int rid = blockIdx.x * 256 + threadIdx.x;   // 0..5119
  const int p = rid / (N_BATCH * O_OUT);
  const int r = rid % (N_BATCH * O_OUT);            // n*20+o
  const float* up = (p == 0) ? u2_m : u2_l;
  float* ob = out + (size_t)r * (2 * T_SMP) + p * T_SMP;
  float pend[15];
  #pragma unroll
  for (int d = 0; d < 15; ++d) pend[d] = 0.0f;
  double e1 = 0.0, e2 = 0.0;
  for (int t = 0; t < T_SMP; ++t) {
    double xv = (double)up[(size_t)t * (N_BATCH * O_OUT) + r];
    e1 = IIR_A * e1 + xv;
    e2 = IIR_A * e2 + e1;
    float uf = (float)(IIR_CK * (e2 - e1));
    float um = uf + pend[0];
    float s  = (um >= 10.0f) ? 1.0f : 0.0f;
    #pragma unroll
    for (int d = 0; d < 14; ++d) pend[d] = fmaf(s, REFN_C[d], pend[d + 1]);
    pend[14] = s * REFN_C[14];
    ob[t] = s;
  }
}

// ---------------------------------------------------------------------------
extern "C" void kernel_launch(void* const* d_in, const int* in_sizes, int n_in,
                              void* d_out, int out_size, void* d_ws, size_t ws_size,
                              hipStream_t stream) {
  const float* x      = (const float*)d_in[0];
  const float* w_fc1  = (const float*)d_in[1];
  const float* w_fc2  = (const float*)d_in[2];
  const float* w_loc1 = (const float*)d_in[3];
  const float* w_loc2 = (const float*)d_in[4];
  float* out = (float*)d_out;
  char* ws = (char*)d_ws;

  // workspace layout (all offsets 256B-aligned)
  uint64_t* xm_m  = (uint64_t*)(ws + 0);         //   638,976
  uint64_t* xm_l  = (uint64_t*)(ws + 638976);    //   638,976
  uint64_t* s1m_m = (uint64_t*)(ws + 1277952);   // 2,555,904
  uint64_t* s1m_l = (uint64_t*)(ws + 3833856);   // 2,555,904
  float*    u2_m  = (float*)   (ws + 6389760);   // 1,597,440
  float*    u2_l  = (float*)   (ws + 7987200);   // 1,597,440  (end 9,584,640)

  hipLaunchKernelGGL(k_masks, dim3(128), dim3(256),
                     C_IN * T_SMP * sizeof(float), stream,
                     x, xm_m, xm_l);
  hipLaunchKernelGGL(k_layer1, dim3(16, 32, 2), dim3(256),
                     0, stream,
                     w_fc1, w_loc1, xm_m, xm_l, s1m_m, s1m_l);
  hipLaunchKernelGGL(k_layer2, dim3(128, 2), dim3(512),
                     H_HID * O_OUT * sizeof(int), stream,
                     w_fc2, w_loc2, s1m_m, s1m_l, u2_m, u2_l);
  hipLaunchKernelGGL(k_psp_spike_out, dim3(20), dim3(256), 0, stream,
                     u2_m, u2_l, out);
}

// Round 7
// 365.012 us; speedup vs baseline: 1.1869x; 1.0143x over previous
//
#include <hip/hip_runtime.h>
#include <stdint.h>

#define N_BATCH 128
#define C_IN    156
#define T_SMP   156
#define H_HID   1024
#define O_OUT   20

// Baked permutation (from reference _top_down construction)
__constant__ int PERM_C[156] = {
  20,21,48,49,68,69,6,7,34,35,58,59,12,13,2,3,38,39,72,73,56,57,22,23,16,17,
  64,65,44,45,30,31,0,1,10,11,28,29,40,41,52,53,66,67,76,77,46,47,32,33,18,19,
  60,61,74,75,54,55,26,27,4,5,42,43,62,63,14,15,36,37,70,71,8,9,24,25,50,51,
  98,99,126,127,146,147,84,85,112,113,136,137,90,91,80,81,116,117,150,151,134,135,
  100,101,94,95,142,143,122,123,108,109,78,79,88,89,106,107,118,119,130,131,144,145,
  154,155,124,125,110,111,96,97,138,139,152,153,132,133,104,105,82,83,120,121,
  140,141,92,93,114,115,148,149,86,87,102,103,128,129
};

// ref_next[d] = REF_KERNEL[d+1] = -20*(d+1)*exp(-d), correctly-rounded fp32
__device__ __constant__ float REFN_C[15] = {
  -20.0f,
  -14.7151776468576930f,
  -8.1201169941967630f,
  -3.9829654694291155f,
  -1.8315638888734178f,
  -0.80855363989025606f,
  -0.34702530473329017f,
  -0.14590111448872258f,
  -0.060383273022452135f,
  -0.024681960817335913f,
  -0.0099879845477466679f,
  -0.0040084081896589585f,
  -0.0015974952118653345f,
  -0.00063348115597555236f,
  -0.00024945861573107036f
};

#define IIR_A  0.904837418035959573   // exp(-1/10)
#define IIR_CK 0.271828182845904524   // e/10

// ---------------------------------------------------------------------------
// K1: build packed active-index lists for both paths (round-4 version).
// Packed 4 u8 indices per u32; padded with 156 (bias-only row in wB).
// ---------------------------------------------------------------------------
__global__ void __launch_bounds__(256) k_build_lists(
    const float* __restrict__ x,
    uint32_t* __restrict__ lists_m, uint32_t* __restrict__ cnt_m,
    uint32_t* __restrict__ lists_l, uint32_t* __restrict__ cnt_l)
{
  extern __shared__ float xl[];            // [156*156]
  const int n = blockIdx.x;
  const float* xn = x + n * (C_IN * T_SMP);
  for (int i = threadIdx.x; i < C_IN * T_SMP; i += 256) xl[i] = xn[i];
  __syncthreads();
  const int t = threadIdx.x;
  if (t < T_SMP) {
    { // main path
      uint32_t* Lp = lists_m + (n * T_SMP + t) * 40;
      uint32_t w = 0; int cnt = 0, nw = 0;
      for (int c = 0; c < C_IN; ++c) {
        if (xl[c * T_SMP + t] > 0.5f) {
          w |= ((uint32_t)c) << ((cnt & 3) * 8);
          ++cnt;
          if ((cnt & 3) == 0) { Lp[nw++] = w; w = 0; }
        }
      }
      if (cnt & 3) {
        for (int k = cnt & 3; k < 4; ++k) w |= 156u << (k * 8);
        Lp[nw++] = w;
      }
      cnt_m[n * T_SMP + t] = (uint32_t)nw;
    }
    { // location path
      uint32_t* Lp = lists_l + (n * T_SMP + t) * 40;
      const int pc = PERM_C[t];
      uint32_t w = 0; int cnt = 0, nw = 0;
      for (int tau = 0; tau < T_SMP; ++tau) {
        if (xl[pc * T_SMP + tau] > 0.5f) {
          w |= ((uint32_t)tau) << ((cnt & 3) * 8);
          ++cnt;
          if ((cnt & 3) == 0) { Lp[nw++] = w; w = 0; }
        }
      }
      if (cnt & 3) {
        for (int k = cnt & 3; k < 4; ++k) w |= 156u << (k * 8);
        Lp[nw++] = w;
      }
      cnt_l[n * T_SMP + t] = (uint32_t)nw;
    }
  }
}

// ---------------------------------------------------------------------------
// K2 v7: fused layer-1 = round-4 parallel-load structure + biased-u32 table.
// wB[c*64+lane] = round(w[h0+lane][c]*2^28) + 2^31 (u32). Guard row (index
// 156) = 2^31, so every processed slot (incl. padding) adds exactly one bias
// -> Sw = (a0+a1) - 4*nw*2^31. Integer adds: order-independent, exact; same
// quantization as round 6 (passed absmax 0) -> identical spikes.
// Per term: 1 addr VALU + ds_read_b32 (conflict-free) + add_co/addc.
// 40.2KB LDS -> 4 blocks/CU = 16 waves/CU. Unrolled 8-word DOWORD keeps
// 4 independent LDS loads in flight (the thing round 6 lost).
// ---------------------------------------------------------------------------
__global__ void __launch_bounds__(256, 4) k_layer1(
    const float* __restrict__ w_fc1, const float* __restrict__ w_loc1,
    const uint32_t* __restrict__ lists_m, const uint32_t* __restrict__ cnt_m,
    const uint32_t* __restrict__ lists_l, const uint32_t* __restrict__ cnt_l,
    uint64_t* __restrict__ s1m_m, uint64_t* __restrict__ s1m_l)
{
  extern __shared__ uint32_t wB[];         // [157][64]
  const int hc   = blockIdx.x;             // 0..15 (h chunk of 64)
  const int n0   = blockIdx.y * 4;
  const int path = blockIdx.z;
  const int tid  = threadIdx.x;
  const float* w = (path == 0) ? w_fc1 : w_loc1;
  const uint32_t* lists = (path == 0) ? lists_m : lists_l;
  const uint32_t* cnts  = (path == 0) ? cnt_m  : cnt_l;
  uint64_t* s1m = (path == 0) ? s1m_m : s1m_l;
  const int h0 = hc * 64;

  { // stage: thread tid owns h-row hp = tid&63, c-quarter = tid>>6 (39 c each)
    const int hp = tid & 63;
    const int c0 = (tid >> 6) * 39;
    const float* wr = w + (size_t)(h0 + hp) * C_IN + c0;
    #pragma unroll
    for (int k = 0; k < 39; ++k) {
      int q = __double2int_rn((double)wr[k] * 0x1p28);
      wB[(c0 + k) * 64 + hp] = (uint32_t)q + 0x80000000u;
    }
    if (tid < 64) wB[156 * 64 + tid] = 0x80000000u;  // guard row = bias only
  }
  __syncthreads();

  const int wv   = tid >> 6;               // wave -> batch offset
  const int lane = tid & 63;
  const int n    = n0 + wv;
  const int rbase = n * T_SMP;

  float pend[15];
  #pragma unroll
  for (int d = 0; d < 15; ++d) pend[d] = 0.0f;
  double e1 = 0.0, e2 = 0.0;

  // prefetch t=0 list
  int nw = (int)cnts[rbase];
  uint4 pkA = *(const uint4*)(lists + (size_t)rbase * 40);
  uint4 pkB = *(const uint4*)(lists + (size_t)rbase * 40 + 4);

  for (int t = 0; t < T_SMP; ++t) {
    const int base = rbase + t;
    const int basen = (t < T_SMP - 1) ? base + 1 : base;
    const int nw_n = (int)cnts[basen];
    const uint4 pkA_n = *(const uint4*)(lists + (size_t)basen * 40);
    const uint4 pkB_n = *(const uint4*)(lists + (size_t)basen * 40 + 4);

    uint64_t a0 = 0, a1 = 0;

#define DOWORD(PK) do {                                                      \
    uint32_t pk_ = __builtin_amdgcn_readfirstlane(PK);                       \
    int c0_ = pk_ & 255, c1_ = (pk_ >> 8) & 255,                             \
        c2_ = (pk_ >> 16) & 255, c3_ = pk_ >> 24;                            \
    uint32_t F0 = wB[c0_ * 64 + lane];                                       \
    uint32_t F1 = wB[c1_ * 64 + lane];                                       \
    uint32_t F2 = wB[c2_ * 64 + lane];                                       \
    uint32_t F3 = wB[c3_ * 64 + lane];                                       \
    a0 += (uint64_t)F0 + (uint64_t)F2;                                       \
    a1 += (uint64_t)F1 + (uint64_t)F3;                                       \
  } while (0)

    if (nw > 0) DOWORD(pkA.x);
    if (nw > 1) DOWORD(pkA.y);
    if (nw > 2) DOWORD(pkA.z);
    if (nw > 3) DOWORD(pkA.w);
    if (nw > 4) DOWORD(pkB.x);
    if (nw > 5) DOWORD(pkB.y);
    if (nw > 6) DOWORD(pkB.z);
    if (nw > 7) DOWORD(pkB.w);
    if (nw > 8) {   // rare tail (>32 active channels)
      const uint32_t* Lp = lists + (size_t)base * 40;
      for (int wi = 8; wi < nw; ++wi) DOWORD(Lp[wi]);
    }
#undef DOWORD

    long long sw = (long long)(a0 + a1 - ((uint64_t)(4 * nw) << 31));
    double upre = (double)sw * 0x1p-28;
    e1 = IIR_A * e1 + upre;
    e2 = IIR_A * e2 + e1;
    float uf = (float)(IIR_CK * (e2 - e1));
    float um = uf + pend[0];
    bool sp = (um >= 10.0f);
    float s = sp ? 1.0f : 0.0f;
    #pragma unroll
    for (int d = 0; d < 14; ++d) pend[d] = fmaf(s, REFN_C[d], pend[d + 1]);
    pend[14] = s * REFN_C[14];
    uint64_t bal = __ballot(sp);
    if (lane == 0) s1m[(size_t)base * 16 + hc] = bal;

    nw = nw_n; pkA = pkA_n; pkB = pkB_n;
  }
}

// ---------------------------------------------------------------------------
// K3 v7: layer-2 dense via bitmask. Per spike-bit: ONE ds_read_b128 (4 o)
// + ONE ds_read_b32 (5th o) instead of 5 scattered b32.
// w2a[h*4+og] = int4{w2[og],w2[og+4],w2[og+8],w2[og+12]}[h], w2b[h*4+og] =
// w2[og+16][h], both scaled 2^31. ONE block per (n,path), 8 waves over t.
// ---------------------------------------------------------------------------
__global__ void __launch_bounds__(512, 1) k_layer2(
    const float* __restrict__ w_fc2, const float* __restrict__ w_loc2,
    const uint64_t* __restrict__ s1m_m, const uint64_t* __restrict__ s1m_l,
    float* __restrict__ u2_m, float* __restrict__ u2_l)
{
  extern __shared__ int4 w2a[];            // [1024*4] int4  (64KB)
  int* w2b = (int*)&w2a[H_HID * 4];        // [1024*4] int   (16KB)
  const int path = blockIdx.y;
  const int n = blockIdx.x;
  const float* w2 = (path == 0) ? w_fc2 : w_loc2;
  const uint64_t* s1m = (path == 0) ? s1m_m : s1m_l;
  float* u2 = (path == 0) ? u2_m : u2_l;
  for (int i = threadIdx.x; i < H_HID * 4; i += 512) {
    const int h = i >> 2, og = i & 3;
    int4 v;
    v.x = __double2int_rn((double)w2[(og +  0) * H_HID + h] * 0x1p31);
    v.y = __double2int_rn((double)w2[(og +  4) * H_HID + h] * 0x1p31);
    v.z = __double2int_rn((double)w2[(og +  8) * H_HID + h] * 0x1p31);
    v.w = __double2int_rn((double)w2[(og + 12) * H_HID + h] * 0x1p31);
    w2a[i] = v;
    w2b[i] = __double2int_rn((double)w2[(og + 16) * H_HID + h] * 0x1p31);
  }
  __syncthreads();
  const int wv   = threadIdx.x >> 6;
  const int lane = threadIdx.x & 63;
  const int hw = lane >> 2, og = lane & 3;

  for (int t = wv; t < T_SMP; t += 8) {
    const int id = n * T_SMP + t;
    uint64_t m = s1m[(size_t)id * 16 + hw];
    long long acc0 = 0, acc1 = 0, acc2 = 0, acc3 = 0, acc4 = 0;
    while (m) {
      int b = __builtin_ctzll(m);
      m &= m - 1;
      const int h = hw * 64 + b;
      const int4 va = w2a[h * 4 + og];
      const int  vb = w2b[h * 4 + og];
      acc0 += va.x;
      acc1 += va.y;
      acc2 += va.z;
      acc3 += va.w;
      acc4 += vb;
    }
    #pragma unroll
    for (int off = 4; off <= 32; off <<= 1) {
      acc0 += __shfl_xor(acc0, off);
      acc1 += __shfl_xor(acc1, off);
      acc2 += __shfl_xor(acc2, off);
      acc3 += __shfl_xor(acc3, off);
      acc4 += __shfl_xor(acc4, off);
    }
    if (lane < 4) {
      float* ub = u2 + (size_t)t * (N_BATCH * O_OUT) + n * O_OUT + og;
      ub[0]  = (float)((double)acc0 * 0x1p-31);
      ub[4]  = (float)((double)acc1 * 0x1p-31);
      ub[8]  = (float)((double)acc2 * 0x1p-31);
      ub[12] = (float)((double)acc3 * 0x1p-31);
      ub[16] = (float)((double)acc4 * 0x1p-31);
    }
  }
}

// ---------------------------------------------------------------------------
// K4: layer-2 psp (fp64 IIR) + spike scan, write concatenated output.
// u2 is t-major -> per-t loads are coalesced across the 5120 threads.
// ---------------------------------------------------------------------------
__global__ void __launch_bounds__(256) k_psp_spike_out(
    const float* __restrict__ u2_m, const float* __restrict__ u2_l,
    float* __restrict__ out)
{
  const int rid = blockIdx.x * 256 + threadIdx.x;   // 0..5119
  const int p = rid / (N_BATCH * O_OUT);
  const int r = rid % (N_BATCH * O_OUT);            // n*20+o
  const float* up = (p == 0) ? u2_m : u2_l;
  float* ob = out + (size_t)r * (2 * T_SMP) + p * T_SMP;
  float pend[15];
  #pragma unroll
  for (int d = 0; d < 15; ++d) pend[d] = 0.0f;
  double e1 = 0.0, e2 = 0.0;
  for (int t = 0; t < T_SMP; ++t) {
    double xv = (double)up[(size_t)t * (N_BATCH * O_OUT) + r];
    e1 = IIR_A * e1 + xv;
    e2 = IIR_A * e2 + e1;
    float uf = (float)(IIR_CK * (e2 - e1));
    float um = uf + pend[0];
    float s  = (um >= 10.0f) ? 1.0f : 0.0f;
    #pragma unroll
    for (int d = 0; d < 14; ++d) pend[d] = fmaf(s, REFN_C[d], pend[d + 1]);
    pend[14] = s * REFN_C[14];
    ob[t] = s;
  }
}

// ---------------------------------------------------------------------------
extern "C" void kernel_launch(void* const* d_in, const int* in_sizes, int n_in,
                              void* d_out, int out_size, void* d_ws, size_t ws_size,
                              hipStream_t stream) {
  const float* x      = (const float*)d_in[0];
  const float* w_fc1  = (const float*)d_in[1];
  const float* w_fc2  = (const float*)d_in[2];
  const float* w_loc1 = (const float*)d_in[3];
  const float* w_loc2 = (const float*)d_in[4];
  float* out = (float*)d_out;
  char* ws = (char*)d_ws;

  // workspace layout
  uint32_t* lists_m = (uint32_t*)(ws + 0);          //  3,194,880
  uint32_t* lists_l = (uint32_t*)(ws + 3194880);    //  3,194,880
  uint32_t* cnt_m   = (uint32_t*)(ws + 6389760);    //     79,872
  uint32_t* cnt_l   = (uint32_t*)(ws + 6469632);    //     79,872
  uint64_t* s1m_m   = (uint64_t*)(ws + 6549504);    //  2,555,904
  uint64_t* s1m_l   = (uint64_t*)(ws + 9105408);    //  2,555,904
  float*    u2_m    = (float*)   (ws + 11661312);   //  1,597,440
  float*    u2_l    = (float*)   (ws + 13258752);   //  1,597,440

  hipLaunchKernelGGL(k_build_lists, dim3(128), dim3(256),
                     C_IN * T_SMP * sizeof(float), stream,
                     x, lists_m, cnt_m, lists_l, cnt_l);
  hipLaunchKernelGGL(k_layer1, dim3(16, 32, 2), dim3(256),
                     157 * 64 * sizeof(uint32_t), stream,
                     w_fc1, w_loc1, lists_m, cnt_m, lists_l, cnt_l, s1m_m, s1m_l);
  hipLaunchKernelGGL(k_layer2, dim3(128, 2), dim3(512),
                     H_HID * 4 * sizeof(int4) + H_HID * 4 * sizeof(int), stream,
                     w_fc2, w_loc2, s1m_m, s1m_l, u2_m, u2_l);
  hipLaunchKernelGGL(k_psp_spike_out, dim3(20), dim3(256), 0, stream,
                     u2_m, u2_l, out);
}

// Round 8
// 357.530 us; speedup vs baseline: 1.2117x; 1.0209x over previous
//
#include <hip/hip_runtime.h>
#include <stdint.h>

#define N_BATCH 128
#define C_IN    156
#define T_SMP   156
#define H_HID   1024
#define O_OUT   20

// Baked permutation (from reference _top_down construction)
__constant__ int PERM_C[156] = {
  20,21,48,49,68,69,6,7,34,35,58,59,12,13,2,3,38,39,72,73,56,57,22,23,16,17,
  64,65,44,45,30,31,0,1,10,11,28,29,40,41,52,53,66,67,76,77,46,47,32,33,18,19,
  60,61,74,75,54,55,26,27,4,5,42,43,62,63,14,15,36,37,70,71,8,9,24,25,50,51,
  98,99,126,127,146,147,84,85,112,113,136,137,90,91,80,81,116,117,150,151,134,135,
  100,101,94,95,142,143,122,123,108,109,78,79,88,89,106,107,118,119,130,131,144,145,
  154,155,124,125,110,111,96,97,138,139,152,153,132,133,104,105,82,83,120,121,
  140,141,92,93,114,115,148,149,86,87,102,103,128,129
};

// ref_next[d] = REF_KERNEL[d+1] = -20*(d+1)*exp(-d), correctly-rounded fp32
__device__ __constant__ float REFN_C[15] = {
  -20.0f,
  -14.7151776468576930f,
  -8.1201169941967630f,
  -3.9829654694291155f,
  -1.8315638888734178f,
  -0.80855363989025606f,
  -0.34702530473329017f,
  -0.14590111448872258f,
  -0.060383273022452135f,
  -0.024681960817335913f,
  -0.0099879845477466679f,
  -0.0040084081896589585f,
  -0.0015974952118653345f,
  -0.00063348115597555236f,
  -0.00024945861573107036f
};

#define IIR_A  0.904837418035959573   // exp(-1/10)
#define IIR_CK 0.271828182845904524   // e/10
#define GUARD_WORD 0x9C9C9C9Cu        // 4 x index 156 (bias-only guard row)

// ---------------------------------------------------------------------------
// K1: build packed active-index lists, PADDED to >=6 words with guard slots.
// Every slot (real or guard) contributes exactly one 2^31 bias in K2 ->
// constant de-bias when nw<=6. cnt keeps the real word count for the tail.
// ---------------------------------------------------------------------------
__global__ void __launch_bounds__(256) k_build_lists(
    const float* __restrict__ x,
    uint32_t* __restrict__ lists_m, uint32_t* __restrict__ cnt_m,
    uint32_t* __restrict__ lists_l, uint32_t* __restrict__ cnt_l)
{
  extern __shared__ float xl[];            // [156*156]
  const int n = blockIdx.x;
  const float* xn = x + n * (C_IN * T_SMP);
  for (int i = threadIdx.x; i < C_IN * T_SMP; i += 256) xl[i] = xn[i];
  __syncthreads();
  const int t = threadIdx.x;
  if (t < T_SMP) {
    { // main path
      uint32_t* Lp = lists_m + (n * T_SMP + t) * 40;
      uint32_t w = 0; int cnt = 0, nw = 0;
      for (int c = 0; c < C_IN; ++c) {
        if (xl[c * T_SMP + t] > 0.5f) {
          w |= ((uint32_t)c) << ((cnt & 3) * 8);
          ++cnt;
          if ((cnt & 3) == 0) { Lp[nw++] = w; w = 0; }
        }
      }
      if (cnt & 3) {
        for (int k = cnt & 3; k < 4; ++k) w |= 156u << (k * 8);
        Lp[nw++] = w;
      }
      cnt_m[n * T_SMP + t] = (uint32_t)nw;
      for (int k = nw; k < 6; ++k) Lp[k] = GUARD_WORD;
    }
    { // location path
      uint32_t* Lp = lists_l + (n * T_SMP + t) * 40;
      const int pc = PERM_C[t];
      uint32_t w = 0; int cnt = 0, nw = 0;
      for (int tau = 0; tau < T_SMP; ++tau) {
        if (xl[pc * T_SMP + tau] > 0.5f) {
          w |= ((uint32_t)tau) << ((cnt & 3) * 8);
          ++cnt;
          if ((cnt & 3) == 0) { Lp[nw++] = w; w = 0; }
        }
      }
      if (cnt & 3) {
        for (int k = cnt & 3; k < 4; ++k) w |= 156u << (k * 8);
        Lp[nw++] = w;
      }
      cnt_l[n * T_SMP + t] = (uint32_t)nw;
      for (int k = nw; k < 6; ++k) Lp[k] = GUARD_WORD;
    }
  }
}

// ---------------------------------------------------------------------------
// K2 v8: fused layer-1, straight-line 24-slot gather.
// wB[c*64+lane] = round(w[h0+lane][c]*2^28) + 2^31 (u32); guard row = 2^31.
// 6 unconditional DOWORDs = 24 independent conflict-free ds_read_b32 in
// flight; index extraction on SALU (readfirstlane'd words); de-bias is the
// CONSTANT 24*2^31 (nw<=6; rare tail extends slots to 4*nw). Integer sum ->
// bitwise-identical spikes to rounds 6/7 (absmax 0).
// 40.2KB LDS -> 4 blocks/CU. Block = 4 waves = 4 batches.
// ---------------------------------------------------------------------------
__global__ void __launch_bounds__(256, 4) k_layer1(
    const float* __restrict__ w_fc1, const float* __restrict__ w_loc1,
    const uint32_t* __restrict__ lists_m, const uint32_t* __restrict__ cnt_m,
    const uint32_t* __restrict__ lists_l, const uint32_t* __restrict__ cnt_l,
    uint64_t* __restrict__ s1m_m, uint64_t* __restrict__ s1m_l)
{
  extern __shared__ uint32_t wB[];         // [157][64]
  const int hc   = blockIdx.x;             // 0..15 (h chunk of 64)
  const int n0   = blockIdx.y * 4;
  const int path = blockIdx.z;
  const int tid  = threadIdx.x;
  const float* w = (path == 0) ? w_fc1 : w_loc1;
  const uint32_t* lists = (path == 0) ? lists_m : lists_l;
  const uint32_t* cnts  = (path == 0) ? cnt_m  : cnt_l;
  uint64_t* s1m = (path == 0) ? s1m_m : s1m_l;
  const int h0 = hc * 64;

  { // stage: thread tid owns h-row hp = tid&63, c-quarter = tid>>6 (39 c each)
    const int hp = tid & 63;
    const int c0 = (tid >> 6) * 39;
    const float* wr = w + (size_t)(h0 + hp) * C_IN + c0;
    #pragma unroll
    for (int k = 0; k < 39; ++k) {
      int q = __double2int_rn((double)wr[k] * 0x1p28);
      wB[(c0 + k) * 64 + hp] = (uint32_t)q + 0x80000000u;
    }
    if (tid < 64) wB[156 * 64 + tid] = 0x80000000u;  // guard row = bias only
  }
  __syncthreads();

  const int wv   = tid >> 6;               // wave -> batch offset
  const int lane = tid & 63;
  const int n    = n0 + wv;
  const int rbase = n * T_SMP;

  float pend[15];
  #pragma unroll
  for (int d = 0; d < 15; ++d) pend[d] = 0.0f;
  double e1 = 0.0, e2 = 0.0;

  // prefetch t=0 list (words 0..5) + count
  int nw = (int)cnts[rbase];
  uint4 pkA = *(const uint4*)(lists + (size_t)rbase * 40);
  uint2 pkB = *(const uint2*)(lists + (size_t)rbase * 40 + 4);

  for (int t = 0; t < T_SMP; ++t) {
    const int base = rbase + t;
    const int basen = (t < T_SMP - 1) ? base + 1 : base;
    const int nw_n = (int)cnts[basen];
    const uint4 pkA_n = *(const uint4*)(lists + (size_t)basen * 40);
    const uint2 pkB_n = *(const uint2*)(lists + (size_t)basen * 40 + 4);

    uint64_t a0 = 0, a1 = 0;

#define DOWORD(PK) do {                                                      \
    uint32_t pk_ = __builtin_amdgcn_readfirstlane(PK);                       \
    int c0_ = pk_ & 255, c1_ = (pk_ >> 8) & 255,                             \
        c2_ = (pk_ >> 16) & 255, c3_ = pk_ >> 24;                            \
    uint32_t F0 = wB[c0_ * 64 + lane];                                       \
    uint32_t F1 = wB[c1_ * 64 + lane];                                       \
    uint32_t F2 = wB[c2_ * 64 + lane];                                       \
    uint32_t F3 = wB[c3_ * 64 + lane];                                       \
    a0 += (uint64_t)F0 + (uint64_t)F2;                                       \
    a1 += (uint64_t)F1 + (uint64_t)F3;                                       \
  } while (0)

    // straight line: 24 slots, no branches
    DOWORD(pkA.x);
    DOWORD(pkA.y);
    DOWORD(pkA.z);
    DOWORD(pkA.w);
    DOWORD(pkB.x);
    DOWORD(pkB.y);
    uint64_t slots = 24;
    if (nw > 6) {   // rare tail (>24 active channels, ~0.8% of t)
      const uint32_t* Lp = lists + (size_t)base * 40;
      for (int wi = 6; wi < nw; ++wi) DOWORD(Lp[wi]);
      slots = (uint64_t)(4 * nw);
    }
#undef DOWORD

    long long sw = (long long)(a0 + a1 - (slots << 31));
    double upre = (double)sw * 0x1p-28;
    e1 = IIR_A * e1 + upre;
    e2 = IIR_A * e2 + e1;
    float uf = (float)(IIR_CK * (e2 - e1));
    float um = uf + pend[0];
    bool sp = (um >= 10.0f);
    float s = sp ? 1.0f : 0.0f;
    #pragma unroll
    for (int d = 0; d < 14; ++d) pend[d] = fmaf(s, REFN_C[d], pend[d + 1]);
    pend[14] = s * REFN_C[14];
    uint64_t bal = __ballot(sp);
    if (lane == 0) s1m[(size_t)base * 16 + hc] = bal;

    nw = nw_n; pkA = pkA_n; pkB = pkB_n;
  }
}

// ---------------------------------------------------------------------------
// K3 v7: layer-2 dense via bitmask. Per spike-bit: ONE ds_read_b128 (4 o)
// + ONE ds_read_b32 (5th o). ONE block per (n,path), 8 waves over t.
// ---------------------------------------------------------------------------
__global__ void __launch_bounds__(512, 1) k_layer2(
    const float* __restrict__ w_fc2, const float* __restrict__ w_loc2,
    const uint64_t* __restrict__ s1m_m, const uint64_t* __restrict__ s1m_l,
    float* __restrict__ u2_m, float* __restrict__ u2_l)
{
  extern __shared__ int4 w2a[];            // [1024*4] int4  (64KB)
  int* w2b = (int*)&w2a[H_HID * 4];        // [1024*4] int   (16KB)
  const int path = blockIdx.y;
  const int n = blockIdx.x;
  const float* w2 = (path == 0) ? w_fc2 : w_loc2;
  const uint64_t* s1m = (path == 0) ? s1m_m : s1m_l;
  float* u2 = (path == 0) ? u2_m : u2_l;
  for (int i = threadIdx.x; i < H_HID * 4; i += 512) {
    const int h = i >> 2, og = i & 3;
    int4 v;
    v.x = __double2int_rn((double)w2[(og +  0) * H_HID + h] * 0x1p31);
    v.y = __double2int_rn((double)w2[(og +  4) * H_HID + h] * 0x1p31);
    v.z = __double2int_rn((double)w2[(og +  8) * H_HID + h] * 0x1p31);
    v.w = __double2int_rn((double)w2[(og + 12) * H_HID + h] * 0x1p31);
    w2a[i] = v;
    w2b[i] = __double2int_rn((double)w2[(og + 16) * H_HID + h] * 0x1p31);
  }
  __syncthreads();
  const int wv   = threadIdx.x >> 6;
  const int lane = threadIdx.x & 63;
  const int hw = lane >> 2, og = lane & 3;

  for (int t = wv; t < T_SMP; t += 8) {
    const int id = n * T_SMP + t;
    uint64_t m = s1m[(size_t)id * 16 + hw];
    long long acc0 = 0, acc1 = 0, acc2 = 0, acc3 = 0, acc4 = 0;
    while (m) {
      int b = __builtin_ctzll(m);
      m &= m - 1;
      const int h = hw * 64 + b;
      const int4 va = w2a[h * 4 + og];
      const int  vb = w2b[h * 4 + og];
      acc0 += va.x;
      acc1 += va.y;
      acc2 += va.z;
      acc3 += va.w;
      acc4 += vb;
    }
    #pragma unroll
    for (int off = 4; off <= 32; off <<= 1) {
      acc0 += __shfl_xor(acc0, off);
      acc1 += __shfl_xor(acc1, off);
      acc2 += __shfl_xor(acc2, off);
      acc3 += __shfl_xor(acc3, off);
      acc4 += __shfl_xor(acc4, off);
    }
    if (lane < 4) {
      float* ub = u2 + (size_t)t * (N_BATCH * O_OUT) + n * O_OUT + og;
      ub[0]  = (float)((double)acc0 * 0x1p-31);
      ub[4]  = (float)((double)acc1 * 0x1p-31);
      ub[8]  = (float)((double)acc2 * 0x1p-31);
      ub[12] = (float)((double)acc3 * 0x1p-31);
      ub[16] = (float)((double)acc4 * 0x1p-31);
    }
  }
}

// ---------------------------------------------------------------------------
// K4: layer-2 psp (fp64 IIR) + spike scan, write concatenated output.
// ---------------------------------------------------------------------------
__global__ void __launch_bounds__(256) k_psp_spike_out(
    const float* __restrict__ u2_m, const float* __restrict__ u2_l,
    float* __restrict__ out)
{
  const int rid = blockIdx.x * 256 + threadIdx.x;   // 0..5119
  const int p = rid / (N_BATCH * O_OUT);
  const int r = rid % (N_BATCH * O_OUT);            // n*20+o
  const float* up = (p == 0) ? u2_m : u2_l;
  float* ob = out + (size_t)r * (2 * T_SMP) + p * T_SMP;
  float pend[15];
  #pragma unroll
  for (int d = 0; d < 15; ++d) pend[d] = 0.0f;
  double e1 = 0.0, e2 = 0.0;
  for (int t = 0; t < T_SMP; ++t) {
    double xv = (double)up[(size_t)t * (N_BATCH * O_OUT) + r];
    e1 = IIR_A * e1 + xv;
    e2 = IIR_A * e2 + e1;
    float uf = (float)(IIR_CK * (e2 - e1));
    float um = uf + pend[0];
    float s  = (um >= 10.0f) ? 1.0f : 0.0f;
    #pragma unroll
    for (int d = 0; d < 14; ++d) pend[d] = fmaf(s, REFN_C[d], pend[d + 1]);
    pend[14] = s * REFN_C[14];
    ob[t] = s;
  }
}

// ---------------------------------------------------------------------------
extern "C" void kernel_launch(void* const* d_in, const int* in_sizes, int n_in,
                              void* d_out, int out_size, void* d_ws, size_t ws_size,
                              hipStream_t stream) {
  const float* x      = (const float*)d_in[0];
  const float* w_fc1  = (const float*)d_in[1];
  const float* w_fc2  = (const float*)d_in[2];
  const float* w_loc1 = (const float*)d_in[3];
  const float* w_loc2 = (const float*)d_in[4];
  float* out = (float*)d_out;
  char* ws = (char*)d_ws;

  // workspace layout
  uint32_t* lists_m = (uint32_t*)(ws + 0);          //  3,194,880
  uint32_t* lists_l = (uint32_t*)(ws + 3194880);    //  3,194,880
  uint32_t* cnt_m   = (uint32_t*)(ws + 6389760);    //     79,872
  uint32_t* cnt_l   = (uint32_t*)(ws + 6469632);    //     79,872
  uint64_t* s1m_m   = (uint64_t*)(ws + 6549504);    //  2,555,904
  uint64_t* s1m_l   = (uint64_t*)(ws + 9105408);    //  2,555,904
  float*    u2_m    = (float*)   (ws + 11661312);   //  1,597,440
  float*    u2_l    = (float*)   (ws + 13258752);   //  1,597,440

  hipLaunchKernelGGL(k_build_lists, dim3(128), dim3(256),
                     C_IN * T_SMP * sizeof(float), stream,
                     x, lists_m, cnt_m, lists_l, cnt_l);
  hipLaunchKernelGGL(k_layer1, dim3(16, 32, 2), dim3(256),
                     157 * 64 * sizeof(uint32_t), stream,
                     w_fc1, w_loc1, lists_m, cnt_m, lists_l, cnt_l, s1m_m, s1m_l);
  hipLaunchKernelGGL(k_layer2, dim3(128, 2), dim3(512),
                     H_HID * 4 * sizeof(int4) + H_HID * 4 * sizeof(int), stream,
                     w_fc2, w_loc2, s1m_m, s1m_l, u2_m, u2_l);
  hipLaunchKernelGGL(k_psp_spike_out, dim3(20), dim3(256), 0, stream,
                     u2_m, u2_l, out);
}

// Round 9
// 338.065 us; speedup vs baseline: 1.2815x; 1.0576x over previous
//
#include <hip/hip_runtime.h>
#include <stdint.h>

#define N_BATCH 128
#define C_IN    156
#define T_SMP   156
#define H_HID   1024
#define O_OUT   20

// Baked permutation (from reference _top_down construction)
__constant__ int PERM_C[156] = {
  20,21,48,49,68,69,6,7,34,35,58,59,12,13,2,3,38,39,72,73,56,57,22,23,16,17,
  64,65,44,45,30,31,0,1,10,11,28,29,40,41,52,53,66,67,76,77,46,47,32,33,18,19,
  60,61,74,75,54,55,26,27,4,5,42,43,62,63,14,15,36,37,70,71,8,9,24,25,50,51,
  98,99,126,127,146,147,84,85,112,113,136,137,90,91,80,81,116,117,150,151,134,135,
  100,101,94,95,142,143,122,123,108,109,78,79,88,89,106,107,118,119,130,131,144,145,
  154,155,124,125,110,111,96,97,138,139,152,153,132,133,104,105,82,83,120,121,
  140,141,92,93,114,115,148,149,86,87,102,103,128,129
};

// ref_next[d] = REF_KERNEL[d+1] = -20*(d+1)*exp(-d), correctly-rounded fp32
__device__ __constant__ float REFN_C[15] = {
  -20.0f,
  -14.7151776468576930f,
  -8.1201169941967630f,
  -3.9829654694291155f,
  -1.8315638888734178f,
  -0.80855363989025606f,
  -0.34702530473329017f,
  -0.14590111448872258f,
  -0.060383273022452135f,
  -0.024681960817335913f,
  -0.0099879845477466679f,
  -0.0040084081896589585f,
  -0.0015974952118653345f,
  -0.00063348115597555236f,
  -0.00024945861573107036f
};

#define IIR_A  0.904837418035959573   // exp(-1/10)
#define IIR_CK 0.271828182845904524   // e/10
#define GUARD_WORD 0x9C9C9C9Cu        // 4 x index 156 (bias-only guard row)

// ---------------------------------------------------------------------------
// K1: build packed active-index lists, PADDED to >=6 words with guard slots.
// ---------------------------------------------------------------------------
__global__ void __launch_bounds__(256) k_build_lists(
    const float* __restrict__ x,
    uint32_t* __restrict__ lists_m, uint32_t* __restrict__ cnt_m,
    uint32_t* __restrict__ lists_l, uint32_t* __restrict__ cnt_l)
{
  extern __shared__ float xl[];            // [156*156]
  const int n = blockIdx.x;
  const float* xn = x + n * (C_IN * T_SMP);
  for (int i = threadIdx.x; i < C_IN * T_SMP; i += 256) xl[i] = xn[i];
  __syncthreads();
  const int t = threadIdx.x;
  if (t < T_SMP) {
    { // main path
      uint32_t* Lp = lists_m + (n * T_SMP + t) * 40;
      uint32_t w = 0; int cnt = 0, nw = 0;
      for (int c = 0; c < C_IN; ++c) {
        if (xl[c * T_SMP + t] > 0.5f) {
          w |= ((uint32_t)c) << ((cnt & 3) * 8);
          ++cnt;
          if ((cnt & 3) == 0) { Lp[nw++] = w; w = 0; }
        }
      }
      if (cnt & 3) {
        for (int k = cnt & 3; k < 4; ++k) w |= 156u << (k * 8);
        Lp[nw++] = w;
      }
      cnt_m[n * T_SMP + t] = (uint32_t)nw;
      for (int k = nw; k < 6; ++k) Lp[k] = GUARD_WORD;
    }
    { // location path
      uint32_t* Lp = lists_l + (n * T_SMP + t) * 40;
      const int pc = PERM_C[t];
      uint32_t w = 0; int cnt = 0, nw = 0;
      for (int tau = 0; tau < T_SMP; ++tau) {
        if (xl[pc * T_SMP + tau] > 0.5f) {
          w |= ((uint32_t)tau) << ((cnt & 3) * 8);
          ++cnt;
          if ((cnt & 3) == 0) { Lp[nw++] = w; w = 0; }
        }
      }
      if (cnt & 3) {
        for (int k = cnt & 3; k < 4; ++k) w |= 156u << (k * 8);
        Lp[nw++] = w;
      }
      cnt_l[n * T_SMP + t] = (uint32_t)nw;
      for (int k = nw; k < 6; ++k) Lp[k] = GUARD_WORD;
    }
  }
}

// ---------------------------------------------------------------------------
// K2 v9: fused layer-1, straight-line 24-slot gather, SCALAR list path.
// wvu = readfirstlane(wave id) makes n/rbase/list addresses provably
// wave-uniform -> compiler emits s_load (scalar cache) for cnt + 6 words,
// index extraction on SALU, zero vector loads and zero per-word
// readfirstlane in the hot loop. Numerics identical to rounds 6-8
// (biased-u32 table, exact integer sum, constant 24*2^31 de-bias).
// 40.2KB LDS -> 4 blocks/CU. Block = 4 waves = 4 batches.
// ---------------------------------------------------------------------------
__global__ void __launch_bounds__(256, 4) k_layer1(
    const float* __restrict__ w_fc1, const float* __restrict__ w_loc1,
    const uint32_t* __restrict__ lists_m, const uint32_t* __restrict__ cnt_m,
    const uint32_t* __restrict__ lists_l, const uint32_t* __restrict__ cnt_l,
    uint64_t* __restrict__ s1m_m, uint64_t* __restrict__ s1m_l)
{
  extern __shared__ uint32_t wB[];         // [157][64]
  const int hc   = blockIdx.x;             // 0..15 (h chunk of 64)
  const int n0   = blockIdx.y * 4;
  const int path = blockIdx.z;
  const int tid  = threadIdx.x;
  const float* w = (path == 0) ? w_fc1 : w_loc1;
  const uint32_t* lists = (path == 0) ? lists_m : lists_l;
  const uint32_t* cnts  = (path == 0) ? cnt_m  : cnt_l;
  uint64_t* s1m = (path == 0) ? s1m_m : s1m_l;
  const int h0 = hc * 64;

  { // stage: thread tid owns h-row hp = tid&63, c-quarter = tid>>6 (39 c each)
    const int hp = tid & 63;
    const int c0 = (tid >> 6) * 39;
    const float* wr = w + (size_t)(h0 + hp) * C_IN + c0;
    #pragma unroll
    for (int k = 0; k < 39; ++k) {
      int q = __double2int_rn((double)wr[k] * 0x1p28);
      wB[(c0 + k) * 64 + hp] = (uint32_t)q + 0x80000000u;
    }
    if (tid < 64) wB[156 * 64 + tid] = 0x80000000u;  // guard row = bias only
  }
  __syncthreads();

  // wave-uniform scalars: force SGPR residency for all list addressing
  const int wvu  = __builtin_amdgcn_readfirstlane(tid >> 6);
  const int lane = tid & 63;
  const int n    = n0 + wvu;
  const int rbase = n * T_SMP;

  float pend[15];
  #pragma unroll
  for (int d = 0; d < 15; ++d) pend[d] = 0.0f;
  double e1 = 0.0, e2 = 0.0;

  // prefetch t=0 list (words 0..5) + count -- scalar loads
  int nw = (int)cnts[rbase];
  uint4 pkA = *(const uint4*)(lists + (size_t)rbase * 40);
  uint2 pkB = *(const uint2*)(lists + (size_t)rbase * 40 + 4);

  #pragma unroll 2
  for (int t = 0; t < T_SMP; ++t) {
    const int base = rbase + t;
    const int basen = (t < T_SMP - 1) ? base + 1 : base;
    const int nw_n = (int)cnts[basen];
    const uint4 pkA_n = *(const uint4*)(lists + (size_t)basen * 40);
    const uint2 pkB_n = *(const uint2*)(lists + (size_t)basen * 40 + 4);

    uint64_t a0 = 0, a1 = 0;

#define DOWORD(PK) do {                                                      \
    uint32_t pk_ = (PK);                    /* SGPR: extracts on SALU */     \
    int c0_ = pk_ & 255, c1_ = (pk_ >> 8) & 255,                             \
        c2_ = (pk_ >> 16) & 255, c3_ = pk_ >> 24;                            \
    uint32_t F0 = wB[c0_ * 64 + lane];                                       \
    uint32_t F1 = wB[c1_ * 64 + lane];                                       \
    uint32_t F2 = wB[c2_ * 64 + lane];                                       \
    uint32_t F3 = wB[c3_ * 64 + lane];                                       \
    a0 += (uint64_t)F0 + (uint64_t)F2;                                       \
    a1 += (uint64_t)F1 + (uint64_t)F3;                                       \
  } while (0)

    // straight line: 24 slots, no branches
    DOWORD(pkA.x);
    DOWORD(pkA.y);
    DOWORD(pkA.z);
    DOWORD(pkA.w);
    DOWORD(pkB.x);
    DOWORD(pkB.y);
    uint64_t slots = 24;
    if (nw > 6) {   // rare tail (>24 active channels, ~0.8% of t)
      const uint32_t* Lp = lists + (size_t)base * 40;
      for (int wi = 6; wi < nw; ++wi) DOWORD(Lp[wi]);
      slots = (uint64_t)(4 * nw);
    }
#undef DOWORD

    long long sw = (long long)(a0 + a1 - (slots << 31));
    double upre = (double)sw * 0x1p-28;
    e1 = IIR_A * e1 + upre;
    e2 = IIR_A * e2 + e1;
    float uf = (float)(IIR_CK * (e2 - e1));
    float um = uf + pend[0];
    bool sp = (um >= 10.0f);
    float s = sp ? 1.0f : 0.0f;
    #pragma unroll
    for (int d = 0; d < 14; ++d) pend[d] = fmaf(s, REFN_C[d], pend[d + 1]);
    pend[14] = s * REFN_C[14];
    uint64_t bal = __ballot(sp);
    if (lane == 0) s1m[(size_t)base * 16 + hc] = bal;

    nw = nw_n; pkA = pkA_n; pkB = pkB_n;
  }
}

// ---------------------------------------------------------------------------
// K3 v7: layer-2 dense via bitmask. Per spike-bit: ONE ds_read_b128 (4 o)
// + ONE ds_read_b32 (5th o). ONE block per (n,path), 8 waves over t.
// ---------------------------------------------------------------------------
__global__ void __launch_bounds__(512, 1) k_layer2(
    const float* __restrict__ w_fc2, const float* __restrict__ w_loc2,
    const uint64_t* __restrict__ s1m_m, const uint64_t* __restrict__ s1m_l,
    float* __restrict__ u2_m, float* __restrict__ u2_l)
{
  extern __shared__ int4 w2a[];            // [1024*4] int4  (64KB)
  int* w2b = (int*)&w2a[H_HID * 4];        // [1024*4] int   (16KB)
  const int path = blockIdx.y;
  const int n = blockIdx.x;
  const float* w2 = (path == 0) ? w_fc2 : w_loc2;
  const uint64_t* s1m = (path == 0) ? s1m_m : s1m_l;
  float* u2 = (path == 0) ? u2_m : u2_l;
  for (int i = threadIdx.x; i < H_HID * 4; i += 512) {
    const int h = i >> 2, og = i & 3;
    int4 v;
    v.x = __double2int_rn((double)w2[(og +  0) * H_HID + h] * 0x1p31);
    v.y = __double2int_rn((double)w2[(og +  4) * H_HID + h] * 0x1p31);
    v.z = __double2int_rn((double)w2[(og +  8) * H_HID + h] * 0x1p31);
    v.w = __double2int_rn((double)w2[(og + 12) * H_HID + h] * 0x1p31);
    w2a[i] = v;
    w2b[i] = __double2int_rn((double)w2[(og + 16) * H_HID + h] * 0x1p31);
  }
  __syncthreads();
  const int wv   = threadIdx.x >> 6;
  const int lane = threadIdx.x & 63;
  const int hw = lane >> 2, og = lane & 3;

  for (int t = wv; t < T_SMP; t += 8) {
    const int id = n * T_SMP + t;
    uint64_t m = s1m[(size_t)id * 16 + hw];
    long long acc0 = 0, acc1 = 0, acc2 = 0, acc3 = 0, acc4 = 0;
    while (m) {
      int b = __builtin_ctzll(m);
      m &= m - 1;
      const int h = hw * 64 + b;
      const int4 va = w2a[h * 4 + og];
      const int  vb = w2b[h * 4 + og];
      acc0 += va.x;
      acc1 += va.y;
      acc2 += va.z;
      acc3 += va.w;
      acc4 += vb;
    }
    #pragma unroll
    for (int off = 4; off <= 32; off <<= 1) {
      acc0 += __shfl_xor(acc0, off);
      acc1 += __shfl_xor(acc1, off);
      acc2 += __shfl_xor(acc2, off);
      acc3 += __shfl_xor(acc3, off);
      acc4 += __shfl_xor(acc4, off);
    }
    if (lane < 4) {
      float* ub = u2 + (size_t)t * (N_BATCH * O_OUT) + n * O_OUT + og;
      ub[0]  = (float)((double)acc0 * 0x1p-31);
      ub[4]  = (float)((double)acc1 * 0x1p-31);
      ub[8]  = (float)((double)acc2 * 0x1p-31);
      ub[12] = (float)((double)acc3 * 0x1p-31);
      ub[16] = (float)((double)acc4 * 0x1p-31);
    }
  }
}

// ---------------------------------------------------------------------------
// K4: layer-2 psp (fp64 IIR) + spike scan, write concatenated output.
// ---------------------------------------------------------------------------
__global__ void __launch_bounds__(256) k_psp_spike_out(
    const float* __restrict__ u2_m, const float* __restrict__ u2_l,
    float* __restrict__ out)
{
  const int rid = blockIdx.x * 256 + threadIdx.x;   // 0..5119
  const int p = rid / (N_BATCH * O_OUT);
  const int r = rid % (N_BATCH * O_OUT);            // n*20+o
  const float* up = (p == 0) ? u2_m : u2_l;
  float* ob = out + (size_t)r * (2 * T_SMP) + p * T_SMP;
  float pend[15];
  #pragma unroll
  for (int d = 0; d < 15; ++d) pend[d] = 0.0f;
  double e1 = 0.0, e2 = 0.0;
  for (int t = 0; t < T_SMP; ++t) {
    double xv = (double)up[(size_t)t * (N_BATCH * O_OUT) + r];
    e1 = IIR_A * e1 + xv;
    e2 = IIR_A * e2 + e1;
    float uf = (float)(IIR_CK * (e2 - e1));
    float um = uf + pend[0];
    float s  = (um >= 10.0f) ? 1.0f : 0.0f;
    #pragma unroll
    for (int d = 0; d < 14; ++d) pend[d] = fmaf(s, REFN_C[d], pend[d + 1]);
    pend[14] = s * REFN_C[14];
    ob[t] = s;
  }
}

// ---------------------------------------------------------------------------
extern "C" void kernel_launch(void* const* d_in, const int* in_sizes, int n_in,
                              void* d_out, int out_size, void* d_ws, size_t ws_size,
                              hipStream_t stream) {
  const float* x      = (const float*)d_in[0];
  const float* w_fc1  = (const float*)d_in[1];
  const float* w_fc2  = (const float*)d_in[2];
  const float* w_loc1 = (const float*)d_in[3];
  const float* w_loc2 = (const float*)d_in[4];
  float* out = (float*)d_out;
  char* ws = (char*)d_ws;

  // workspace layout
  uint32_t* lists_m = (uint32_t*)(ws + 0);          //  3,194,880
  uint32_t* lists_l = (uint32_t*)(ws + 3194880);    //  3,194,880
  uint32_t* cnt_m   = (uint32_t*)(ws + 6389760);    //     79,872
  uint32_t* cnt_l   = (uint32_t*)(ws + 6469632);    //     79,872
  uint64_t* s1m_m   = (uint64_t*)(ws + 6549504);    //  2,555,904
  uint64_t* s1m_l   = (uint64_t*)(ws + 9105408);    //  2,555,904
  float*    u2_m    = (float*)   (ws + 11661312);   //  1,597,440
  float*    u2_l    = (float*)   (ws + 13258752);   //  1,597,440

  hipLaunchKernelGGL(k_build_lists, dim3(128), dim3(256),
                     C_IN * T_SMP * sizeof(float), stream,
                     x, lists_m, cnt_m, lists_l, cnt_l);
  hipLaunchKernelGGL(k_layer1, dim3(16, 32, 2), dim3(256),
                     157 * 64 * sizeof(uint32_t), stream,
                     w_fc1, w_loc1, lists_m, cnt_m, lists_l, cnt_l, s1m_m, s1m_l);
  hipLaunchKernelGGL(k_layer2, dim3(128, 2), dim3(512),
                     H_HID * 4 * sizeof(int4) + H_HID * 4 * sizeof(int), stream,
                     w_fc2, w_loc2, s1m_m, s1m_l, u2_m, u2_l);
  hipLaunchKernelGGL(k_psp_spike_out, dim3(20), dim3(256), 0, stream,
                     u2_m, u2_l, out);
}

// Round 10
// 315.731 us; speedup vs baseline: 1.3721x; 1.0707x over previous
//
#include <hip/hip_runtime.h>
#include <stdint.h>

#define N_BATCH 128
#define C_IN    156
#define T_SMP   156
#define H_HID   1024
#define O_OUT   20

// Baked permutation (from reference _top_down construction)
__constant__ int PERM_C[156] = {
  20,21,48,49,68,69,6,7,34,35,58,59,12,13,2,3,38,39,72,73,56,57,22,23,16,17,
  64,65,44,45,30,31,0,1,10,11,28,29,40,41,52,53,66,67,76,77,46,47,32,33,18,19,
  60,61,74,75,54,55,26,27,4,5,42,43,62,63,14,15,36,37,70,71,8,9,24,25,50,51,
  98,99,126,127,146,147,84,85,112,113,136,137,90,91,80,81,116,117,150,151,134,135,
  100,101,94,95,142,143,122,123,108,109,78,79,88,89,106,107,118,119,130,131,144,145,
  154,155,124,125,110,111,96,97,138,139,152,153,132,133,104,105,82,83,120,121,
  140,141,92,93,114,115,148,149,86,87,102,103,128,129
};

// ref_next[d] = REF_KERNEL[d+1] = -20*(d+1)*exp(-d), correctly-rounded fp32
__device__ __constant__ float REFN_C[15] = {
  -20.0f,
  -14.7151776468576930f,
  -8.1201169941967630f,
  -3.9829654694291155f,
  -1.8315638888734178f,
  -0.80855363989025606f,
  -0.34702530473329017f,
  -0.14590111448872258f,
  -0.060383273022452135f,
  -0.024681960817335913f,
  -0.0099879845477466679f,
  -0.0040084081896589585f,
  -0.0015974952118653345f,
  -0.00063348115597555236f,
  -0.00024945861573107036f
};

#define IIR_A   0.904837418035959573    // exp(-1/10)
#define IIR_CK  0.271828182845904524    // e/10
// CK * 2^-28 folded into one constant (IIR is linear -> pre-scale upre)
#define CKSCALE (IIR_CK * 0x1p-28)
#define GUARD_WORD 0x9C9C9C9Cu          // 4 x index 156 (bias-only guard row)

// ---------------------------------------------------------------------------
// K1: build packed active-index lists, PADDED to >=6 words with guard slots.
// ---------------------------------------------------------------------------
__global__ void __launch_bounds__(256) k_build_lists(
    const float* __restrict__ x,
    uint32_t* __restrict__ lists_m, uint32_t* __restrict__ cnt_m,
    uint32_t* __restrict__ lists_l, uint32_t* __restrict__ cnt_l)
{
  extern __shared__ float xl[];            // [156*156]
  const int n = blockIdx.x;
  const float* xn = x + n * (C_IN * T_SMP);
  for (int i = threadIdx.x; i < C_IN * T_SMP; i += 256) xl[i] = xn[i];
  __syncthreads();
  const int t = threadIdx.x;
  if (t < T_SMP) {
    { // main path
      uint32_t* Lp = lists_m + (n * T_SMP + t) * 40;
      uint32_t w = 0; int cnt = 0, nw = 0;
      for (int c = 0; c < C_IN; ++c) {
        if (xl[c * T_SMP + t] > 0.5f) {
          w |= ((uint32_t)c) << ((cnt & 3) * 8);
          ++cnt;
          if ((cnt & 3) == 0) { Lp[nw++] = w; w = 0; }
        }
      }
      if (cnt & 3) {
        for (int k = cnt & 3; k < 4; ++k) w |= 156u << (k * 8);
        Lp[nw++] = w;
      }
      cnt_m[n * T_SMP + t] = (uint32_t)nw;
      for (int k = nw; k < 6; ++k) Lp[k] = GUARD_WORD;
    }
    { // location path
      uint32_t* Lp = lists_l + (n * T_SMP + t) * 40;
      const int pc = PERM_C[t];
      uint32_t w = 0; int cnt = 0, nw = 0;
      for (int tau = 0; tau < T_SMP; ++tau) {
        if (xl[pc * T_SMP + tau] > 0.5f) {
          w |= ((uint32_t)tau) << ((cnt & 3) * 8);
          ++cnt;
          if ((cnt & 3) == 0) { Lp[nw++] = w; w = 0; }
        }
      }
      if (cnt & 3) {
        for (int k = cnt & 3; k < 4; ++k) w |= 156u << (k * 8);
        Lp[nw++] = w;
      }
      cnt_l[n * T_SMP + t] = (uint32_t)nw;
      for (int k = nw; k < 6; ++k) Lp[k] = GUARD_WORD;
    }
  }
}

// ---------------------------------------------------------------------------
// K2 v10: fused layer-1 -- instruction diet over v9.
//  - no unroll pragma (v9's unroll-2 bloated the body)
//  - straight-line 5 words (covers nact<=20, ~90%); word 6 from prefetched
//    pkB.y when nw==6 (~8%); memory tail only nw>6 (~0.8%)
//  - u64 accumulate as 4 independent a += F (v_lshl_add_u64-friendly)
//  - CK folded into the i64->f64 scale constant (one mul_f64 removed)
//  - running scalar pointers for cnt/list/s1m (no per-t re-derivation)
// Numerics identical to rounds 6-9 (2^28 biased-u32 table, exact int sum).
// ---------------------------------------------------------------------------
__global__ void __launch_bounds__(256, 4) k_layer1(
    const float* __restrict__ w_fc1, const float* __restrict__ w_loc1,
    const uint32_t* __restrict__ lists_m, const uint32_t* __restrict__ cnt_m,
    const uint32_t* __restrict__ lists_l, const uint32_t* __restrict__ cnt_l,
    uint64_t* __restrict__ s1m_m, uint64_t* __restrict__ s1m_l)
{
  extern __shared__ uint32_t wB[];         // [157][64]
  const int hc   = blockIdx.x;             // 0..15 (h chunk of 64)
  const int n0   = blockIdx.y * 4;
  const int path = blockIdx.z;
  const int tid  = threadIdx.x;
  const float* w = (path == 0) ? w_fc1 : w_loc1;
  const uint32_t* lists = (path == 0) ? lists_m : lists_l;
  const uint32_t* cnts  = (path == 0) ? cnt_m  : cnt_l;
  uint64_t* s1m = (path == 0) ? s1m_m : s1m_l;
  const int h0 = hc * 64;

  { // stage: thread tid owns h-row hp = tid&63, c-quarter = tid>>6 (39 c each)
    const int hp = tid & 63;
    const int c0 = (tid >> 6) * 39;
    const float* wr = w + (size_t)(h0 + hp) * C_IN + c0;
    #pragma unroll
    for (int k = 0; k < 39; ++k) {
      int q = __double2int_rn((double)wr[k] * 0x1p28);
      wB[(c0 + k) * 64 + hp] = (uint32_t)q + 0x80000000u;
    }
    if (tid < 64) wB[156 * 64 + tid] = 0x80000000u;  // guard row = bias only
  }
  __syncthreads();

  // wave-uniform scalars: SGPR residency for all list addressing
  const int wvu  = __builtin_amdgcn_readfirstlane(tid >> 6);
  const int lane = tid & 63;
  const int n    = n0 + wvu;
  const int rbase = n * T_SMP;

  // running scalar pointers (strength-reduced)
  const uint32_t* cp = cnts + rbase;           // cnt cursor
  const uint32_t* lp = lists + (size_t)rbase * 40;  // list cursor
  uint64_t* sp_out = s1m + (size_t)rbase * 16 + hc; // ballot cursor

  float pend[15];
  #pragma unroll
  for (int d = 0; d < 15; ++d) pend[d] = 0.0f;
  double e1 = 0.0, e2 = 0.0;

  // prefetch t=0 list (6 words) + count -- scalar loads
  int nw = (int)cp[0];
  uint4 pkA = *(const uint4*)lp;
  uint2 pkB = *(const uint2*)(lp + 4);

  for (int t = 0; t < T_SMP; ++t) {
    // unclamped prefetch of t+1 (garbage at t=155 never consumed; in-bounds)
    const int nw_n = (int)cp[1];
    const uint4 pkA_n = *(const uint4*)(lp + 40);
    const uint2 pkB_n = *(const uint2*)(lp + 44);

    uint64_t a0 = 0, a1 = 0;

#define DOWORD(PK) do {                                                      \
    uint32_t pk_ = (PK);                    /* SGPR: extracts on SALU */     \
    int c0_ = pk_ & 255, c1_ = (pk_ >> 8) & 255,                             \
        c2_ = (pk_ >> 16) & 255, c3_ = pk_ >> 24;                            \
    uint32_t F0 = wB[c0_ * 64 + lane];                                       \
    uint32_t F1 = wB[c1_ * 64 + lane];                                       \
    uint32_t F2 = wB[c2_ * 64 + lane];                                       \
    uint32_t F3 = wB[c3_ * 64 + lane];                                       \
    a0 += F0; a1 += F1; a0 += F2; a1 += F3;                                  \
  } while (0)

    // straight line: 20 slots (covers nact<=20, ~90% of t)
    DOWORD(pkA.x);
    DOWORD(pkA.y);
    DOWORD(pkA.z);
    DOWORD(pkA.w);
    DOWORD(pkB.x);
    uint64_t slots = 20;
    if (nw > 5) {                   // ~8.5%: word 6 already prefetched
      DOWORD(pkB.y);
      slots = 24;
      if (nw > 6) {                 // ~0.8%: memory tail
        for (int wi = 6; wi < nw; ++wi) DOWORD(lp[wi]);
        slots = (uint64_t)(4 * nw);
      }
    }
#undef DOWORD

    long long sw = (long long)(a0 + a1 - (slots << 31));
    double upre = (double)sw * CKSCALE;        // CK pre-folded (linear IIR)
    e1 = IIR_A * e1 + upre;
    e2 = IIR_A * e2 + e1;
    float uf = (float)(e2 - e1);
    float um = uf + pend[0];
    bool sp = (um >= 10.0f);
    float s = sp ? 1.0f : 0.0f;
    #pragma unroll
    for (int d = 0; d < 14; ++d) pend[d] = fmaf(s, REFN_C[d], pend[d + 1]);
    pend[14] = s * REFN_C[14];
    uint64_t bal = __ballot(sp);
    if (lane == 0) *sp_out = bal;

    nw = nw_n; pkA = pkA_n; pkB = pkB_n;
    cp += 1; lp += 40; sp_out += 16;
  }
}

// ---------------------------------------------------------------------------
// K3 v7: layer-2 dense via bitmask. Per spike-bit: ONE ds_read_b128 (4 o)
// + ONE ds_read_b32 (5th o). ONE block per (n,path), 8 waves over t.
// ---------------------------------------------------------------------------
__global__ void __launch_bounds__(512, 1) k_layer2(
    const float* __restrict__ w_fc2, const float* __restrict__ w_loc2,
    const uint64_t* __restrict__ s1m_m, const uint64_t* __restrict__ s1m_l,
    float* __restrict__ u2_m, float* __restrict__ u2_l)
{
  extern __shared__ int4 w2a[];            // [1024*4] int4  (64KB)
  int* w2b = (int*)&w2a[H_HID * 4];        // [1024*4] int   (16KB)
  const int path = blockIdx.y;
  const int n = blockIdx.x;
  const float* w2 = (path == 0) ? w_fc2 : w_loc2;
  const uint64_t* s1m = (path == 0) ? s1m_m : s1m_l;
  float* u2 = (path == 0) ? u2_m : u2_l;
  for (int i = threadIdx.x; i < H_HID * 4; i += 512) {
    const int h = i >> 2, og = i & 3;
    int4 v;
    v.x = __double2int_rn((double)w2[(og +  0) * H_HID + h] * 0x1p31);
    v.y = __double2int_rn((double)w2[(og +  4) * H_HID + h] * 0x1p31);
    v.z = __double2int_rn((double)w2[(og +  8) * H_HID + h] * 0x1p31);
    v.w = __double2int_rn((double)w2[(og + 12) * H_HID + h] * 0x1p31);
    w2a[i] = v;
    w2b[i] = __double2int_rn((double)w2[(og + 16) * H_HID + h] * 0x1p31);
  }
  __syncthreads();
  const int wv   = threadIdx.x >> 6;
  const int lane = threadIdx.x & 63;
  const int hw = lane >> 2, og = lane & 3;

  for (int t = wv; t < T_SMP; t += 8) {
    const int id = n * T_SMP + t;
    uint64_t m = s1m[(size_t)id * 16 + hw];
    long long acc0 = 0, acc1 = 0, acc2 = 0, acc3 = 0, acc4 = 0;
    while (m) {
      int b = __builtin_ctzll(m);
      m &= m - 1;
      const int h = hw * 64 + b;
      const int4 va = w2a[h * 4 + og];
      const int  vb = w2b[h * 4 + og];
      acc0 += va.x;
      acc1 += va.y;
      acc2 += va.z;
      acc3 += va.w;
      acc4 += vb;
    }
    #pragma unroll
    for (int off = 4; off <= 32; off <<= 1) {
      acc0 += __shfl_xor(acc0, off);
      acc1 += __shfl_xor(acc1, off);
      acc2 += __shfl_xor(acc2, off);
      acc3 += __shfl_xor(acc3, off);
      acc4 += __shfl_xor(acc4, off);
    }
    if (lane < 4) {
      float* ub = u2 + (size_t)t * (N_BATCH * O_OUT) + n * O_OUT + og;
      ub[0]  = (float)((double)acc0 * 0x1p-31);
      ub[4]  = (float)((double)acc1 * 0x1p-31);
      ub[8]  = (float)((double)acc2 * 0x1p-31);
      ub[12] = (float)((double)acc3 * 0x1p-31);
      ub[16] = (float)((double)acc4 * 0x1p-31);
    }
  }
}

// ---------------------------------------------------------------------------
// K4: layer-2 psp (fp64 IIR) + spike scan, write concatenated output.
// ---------------------------------------------------------------------------
__global__ void __launch_bounds__(256) k_psp_spike_out(
    const float* __restrict__ u2_m, const float* __restrict__ u2_l,
    float* __restrict__ out)
{
  const int rid = blockIdx.x * 256 + threadIdx.x;   // 0..5119
  const int p = rid / (N_BATCH * O_OUT);
  const int r = rid % (N_BATCH * O_OUT);            // n*20+o
  const float* up = (p == 0) ? u2_m : u2_l;
  float* ob = out + (size_t)r * (2 * T_SMP) + p * T_SMP;
  float pend[15];
  #pragma unroll
  for (int d = 0; d < 15; ++d) pend[d] = 0.0f;
  double e1 = 0.0, e2 = 0.0;
  for (int t = 0; t < T_SMP; ++t) {
    double xv = (double)up[(size_t)t * (N_BATCH * O_OUT) + r];
    e1 = IIR_A * e1 + xv;
    e2 = IIR_A * e2 + e1;
    float uf = (float)(IIR_CK * (e2 - e1));
    float um = uf + pend[0];
    float s  = (um >= 10.0f) ? 1.0f : 0.0f;
    #pragma unroll
    for (int d = 0; d < 14; ++d) pend[d] = fmaf(s, REFN_C[d], pend[d + 1]);
    pend[14] = s * REFN_C[14];
    ob[t] = s;
  }
}

// ---------------------------------------------------------------------------
extern "C" void kernel_launch(void* const* d_in, const int* in_sizes, int n_in,
                              void* d_out, int out_size, void* d_ws, size_t ws_size,
                              hipStream_t stream) {
  const float* x      = (const float*)d_in[0];
  const float* w_fc1  = (const float*)d_in[1];
  const float* w_fc2  = (const float*)d_in[2];
  const float* w_loc1 = (const float*)d_in[3];
  const float* w_loc2 = (const float*)d_in[4];
  float* out = (float*)d_out;
  char* ws = (char*)d_ws;

  // workspace layout
  uint32_t* lists_m = (uint32_t*)(ws + 0);          //  3,194,880
  uint32_t* lists_l = (uint32_t*)(ws + 3194880);    //  3,194,880
  uint32_t* cnt_m   = (uint32_t*)(ws + 6389760);    //     79,872
  uint32_t* cnt_l   = (uint32_t*)(ws + 6469632);    //     79,872
  uint64_t* s1m_m   = (uint64_t*)(ws + 6549504);    //  2,555,904
  uint64_t* s1m_l   = (uint64_t*)(ws + 9105408);    //  2,555,904
  float*    u2_m    = (float*)   (ws + 11661312);   //  1,597,440
  float*    u2_l    = (float*)   (ws + 13258752);   //  1,597,440

  hipLaunchKernelGGL(k_build_lists, dim3(128), dim3(256),
                     C_IN * T_SMP * sizeof(float), stream,
                     x, lists_m, cnt_m, lists_l, cnt_l);
  hipLaunchKernelGGL(k_layer1, dim3(16, 32, 2), dim3(256),
                     157 * 64 * sizeof(uint32_t), stream,
                     w_fc1, w_loc1, lists_m, cnt_m, lists_l, cnt_l, s1m_m, s1m_l);
  hipLaunchKernelGGL(k_layer2, dim3(128, 2), dim3(512),
                     H_HID * 4 * sizeof(int4) + H_HID * 4 * sizeof(int), stream,
                     w_fc2, w_loc2, s1m_m, s1m_l, u2_m, u2_l);
  hipLaunchKernelGGL(k_psp_spike_out, dim3(20), dim3(256), 0, stream,
                     u2_m, u2_l, out);
}

// Round 11
// 297.819 us; speedup vs baseline: 1.4547x; 1.0601x over previous
//
#include <hip/hip_runtime.h>
#include <stdint.h>

#define N_BATCH 128
#define C_IN    156
#define T_SMP   156
#define H_HID   1024
#define O_OUT   20

// Baked permutation (from reference _top_down construction)
__constant__ int PERM_C[156] = {
  20,21,48,49,68,69,6,7,34,35,58,59,12,13,2,3,38,39,72,73,56,57,22,23,16,17,
  64,65,44,45,30,31,0,1,10,11,28,29,40,41,52,53,66,67,76,77,46,47,32,33,18,19,
  60,61,74,75,54,55,26,27,4,5,42,43,62,63,14,15,36,37,70,71,8,9,24,25,50,51,
  98,99,126,127,146,147,84,85,112,113,136,137,90,91,80,81,116,117,150,151,134,135,
  100,101,94,95,142,143,122,123,108,109,78,79,88,89,106,107,118,119,130,131,144,145,
  154,155,124,125,110,111,96,97,138,139,152,153,132,133,104,105,82,83,120,121,
  140,141,92,93,114,115,148,149,86,87,102,103,128,129
};

// ref_next[d] = REF_KERNEL[d+1] = -20*(d+1)*exp(-d), correctly-rounded fp32
__device__ __constant__ float REFN_C[15] = {
  -20.0f,
  -14.7151776468576930f,
  -8.1201169941967630f,
  -3.9829654694291155f,
  -1.8315638888734178f,
  -0.80855363989025606f,
  -0.34702530473329017f,
  -0.14590111448872258f,
  -0.060383273022452135f,
  -0.024681960817335913f,
  -0.0099879845477466679f,
  -0.0040084081896589585f,
  -0.0015974952118653345f,
  -0.00063348115597555236f,
  -0.00024945861573107036f
};

#define IIR_A   0.904837418035959573    // exp(-1/10)
#define IIR_CK  0.271828182845904524    // e/10
// CK * 2^-23 folded into the i32->f64 scale (IIR is linear)
#define CKSCALE23 (IIR_CK * 0x1p-23)
#define BIAS26  0x04000000u             // 2^26 per-slot bias
#define GUARD_WORD 0x9C9C9C9Cu          // 4 x index 156 (bias-only guard row)

// ---------------------------------------------------------------------------
// K1: build packed active-index lists, PADDED to >=6 words with guard slots.
// ---------------------------------------------------------------------------
__global__ void __launch_bounds__(256) k_build_lists(
    const float* __restrict__ x,
    uint32_t* __restrict__ lists_m, uint32_t* __restrict__ cnt_m,
    uint32_t* __restrict__ lists_l, uint32_t* __restrict__ cnt_l)
{
  extern __shared__ float xl[];            // [156*156]
  const int n = blockIdx.x;
  const float* xn = x + n * (C_IN * T_SMP);
  for (int i = threadIdx.x; i < C_IN * T_SMP; i += 256) xl[i] = xn[i];
  __syncthreads();
  const int t = threadIdx.x;
  if (t < T_SMP) {
    { // main path
      uint32_t* Lp = lists_m + (n * T_SMP + t) * 40;
      uint32_t w = 0; int cnt = 0, nw = 0;
      for (int c = 0; c < C_IN; ++c) {
        if (xl[c * T_SMP + t] > 0.5f) {
          w |= ((uint32_t)c) << ((cnt & 3) * 8);
          ++cnt;
          if ((cnt & 3) == 0) { Lp[nw++] = w; w = 0; }
        }
      }
      if (cnt & 3) {
        for (int k = cnt & 3; k < 4; ++k) w |= 156u << (k * 8);
        Lp[nw++] = w;
      }
      cnt_m[n * T_SMP + t] = (uint32_t)nw;
      for (int k = nw; k < 6; ++k) Lp[k] = GUARD_WORD;
    }
    { // location path
      uint32_t* Lp = lists_l + (n * T_SMP + t) * 40;
      const int pc = PERM_C[t];
      uint32_t w = 0; int cnt = 0, nw = 0;
      for (int tau = 0; tau < T_SMP; ++tau) {
        if (xl[pc * T_SMP + tau] > 0.5f) {
          w |= ((uint32_t)tau) << ((cnt & 3) * 8);
          ++cnt;
          if ((cnt & 3) == 0) { Lp[nw++] = w; w = 0; }
        }
      }
      if (cnt & 3) {
        for (int k = cnt & 3; k < 4; ++k) w |= 156u << (k * 8);
        Lp[nw++] = w;
      }
      cnt_l[n * T_SMP + t] = (uint32_t)nw;
      for (int k = nw; k < 6; ++k) Lp[k] = GUARD_WORD;
    }
  }
}

// ---------------------------------------------------------------------------
// K2 v11: fused layer-1 -- EXACT u32 accumulation (1 v_add_u32 per slot).
// Table: wB[c*64+lane] = round(w[h0+lane][c]*2^23) + 2^26 (u32; |w|<8 ->
// q in [0,2^27]; 24-slot sum < 2^32, exact). Guard row = 2^26.
// De-bias: sw = (i32)(sum - slots*2^26) -- exact by mod-2^32 arithmetic even
// for the rare wrapped tail (|true| << 2^31). One v_cvt_f64_i32, CK*2^-23
// folded into the scale. Quant error <= 2^-24/term (~1e-6 abs at threshold),
// 30x below the f32-conv-reference-vs-f64 gap already tolerated with zero
// flips -> same spikes. 40.2KB LDS, 4 blocks/CU, block = 4 waves = 4 batches.
// ---------------------------------------------------------------------------
__global__ void __launch_bounds__(256, 4) k_layer1(
    const float* __restrict__ w_fc1, const float* __restrict__ w_loc1,
    const uint32_t* __restrict__ lists_m, const uint32_t* __restrict__ cnt_m,
    const uint32_t* __restrict__ lists_l, const uint32_t* __restrict__ cnt_l,
    uint64_t* __restrict__ s1m_m, uint64_t* __restrict__ s1m_l)
{
  extern __shared__ uint32_t wB[];         // [157][64]
  const int hc   = blockIdx.x;             // 0..15 (h chunk of 64)
  const int n0   = blockIdx.y * 4;
  const int path = blockIdx.z;
  const int tid  = threadIdx.x;
  const float* w = (path == 0) ? w_fc1 : w_loc1;
  const uint32_t* lists = (path == 0) ? lists_m : lists_l;
  const uint32_t* cnts  = (path == 0) ? cnt_m  : cnt_l;
  uint64_t* s1m = (path == 0) ? s1m_m : s1m_l;
  const int h0 = hc * 64;

  { // stage: thread tid owns h-row hp = tid&63, c-quarter = tid>>6 (39 c each)
    const int hp = tid & 63;
    const int c0 = (tid >> 6) * 39;
    const float* wr = w + (size_t)(h0 + hp) * C_IN + c0;
    #pragma unroll
    for (int k = 0; k < 39; ++k) {
      int q = __double2int_rn((double)wr[k] * 0x1p23);
      wB[(c0 + k) * 64 + hp] = (uint32_t)q + BIAS26;
    }
    if (tid < 64) wB[156 * 64 + tid] = BIAS26;  // guard row = bias only
  }
  __syncthreads();

  // wave-uniform scalars: SGPR residency for all list addressing
  const int wvu  = __builtin_amdgcn_readfirstlane(tid >> 6);
  const int lane = tid & 63;
  const int n    = n0 + wvu;
  const int rbase = n * T_SMP;

  // running scalar pointers (strength-reduced)
  const uint32_t* cp = cnts + rbase;                // cnt cursor
  const uint32_t* lp = lists + (size_t)rbase * 40;  // list cursor
  uint64_t* sp_out = s1m + (size_t)rbase * 16 + hc; // ballot cursor

  float pend[15];
  #pragma unroll
  for (int d = 0; d < 15; ++d) pend[d] = 0.0f;
  double e1 = 0.0, e2 = 0.0;

  // prefetch t=0 list (6 words) + count -- scalar loads
  int nw = (int)cp[0];
  uint4 pkA = *(const uint4*)lp;
  uint2 pkB = *(const uint2*)(lp + 4);

  for (int t = 0; t < T_SMP; ++t) {
    // unclamped prefetch of t+1 (garbage at t=155 never consumed; in-bounds)
    const int nw_n = (int)cp[1];
    const uint4 pkA_n = *(const uint4*)(lp + 40);
    const uint2 pkB_n = *(const uint2*)(lp + 44);

    uint32_t a0 = 0, a1 = 0, a2 = 0, a3 = 0;

#define DOWORD(PK) do {                                                      \
    uint32_t pk_ = (PK);                    /* SGPR: extracts on SALU */     \
    int c0_ = pk_ & 255, c1_ = (pk_ >> 8) & 255,                             \
        c2_ = (pk_ >> 16) & 255, c3_ = pk_ >> 24;                            \
    uint32_t F0 = wB[c0_ * 64 + lane];                                       \
    uint32_t F1 = wB[c1_ * 64 + lane];                                       \
    uint32_t F2 = wB[c2_ * 64 + lane];                                       \
    uint32_t F3 = wB[c3_ * 64 + lane];                                       \
    a0 += F0; a1 += F1; a2 += F2; a3 += F3;                                  \
  } while (0)

    // straight line: 20 slots (covers nact<=20, ~90% of t)
    DOWORD(pkA.x);
    DOWORD(pkA.y);
    DOWORD(pkA.z);
    DOWORD(pkA.w);
    DOWORD(pkB.x);
    uint32_t slots = 20;
    if (nw > 5) {                   // ~8.5%: word 6 already prefetched
      DOWORD(pkB.y);
      slots = 24;
      if (nw > 6) {                 // ~0.8%: memory tail
        for (int wi = 6; wi < nw; ++wi) DOWORD(lp[wi]);
        slots = (uint32_t)(4 * nw);
      }
    }
#undef DOWORD

    uint32_t sum = (a0 + a1) + (a2 + a3);
    int sw = (int)(sum - (slots << 26));       // exact mod-2^32 de-bias
    double upre = (double)sw * CKSCALE23;      // CK*2^-23 pre-folded
    e1 = IIR_A * e1 + upre;
    e2 = IIR_A * e2 + e1;
    float uf = (float)(e2 - e1);
    float um = uf + pend[0];
    bool sp = (um >= 10.0f);
    float s = sp ? 1.0f : 0.0f;
    #pragma unroll
    for (int d = 0; d < 14; ++d) pend[d] = fmaf(s, REFN_C[d], pend[d + 1]);
    pend[14] = s * REFN_C[14];
    uint64_t bal = __ballot(sp);
    if (lane == 0) *sp_out = bal;

    nw = nw_n; pkA = pkA_n; pkB = pkB_n;
    cp += 1; lp += 40; sp_out += 16;
  }
}

// ---------------------------------------------------------------------------
// K3 v7: layer-2 dense via bitmask. Per spike-bit: ONE ds_read_b128 (4 o)
// + ONE ds_read_b32 (5th o). ONE block per (n,path), 8 waves over t.
// ---------------------------------------------------------------------------
__global__ void __launch_bounds__(512, 1) k_layer2(
    const float* __restrict__ w_fc2, const float* __restrict__ w_loc2,
    const uint64_t* __restrict__ s1m_m, const uint64_t* __restrict__ s1m_l,
    float* __restrict__ u2_m, float* __restrict__ u2_l)
{
  extern __shared__ int4 w2a[];            // [1024*4] int4  (64KB)
  int* w2b = (int*)&w2a[H_HID * 4];        // [1024*4] int   (16KB)
  const int path = blockIdx.y;
  const int n = blockIdx.x;
  const float* w2 = (path == 0) ? w_fc2 : w_loc2;
  const uint64_t* s1m = (path == 0) ? s1m_m : s1m_l;
  float* u2 = (path == 0) ? u2_m : u2_l;
  for (int i = threadIdx.x; i < H_HID * 4; i += 512) {
    const int h = i >> 2, og = i & 3;
    int4 v;
    v.x = __double2int_rn((double)w2[(og +  0) * H_HID + h] * 0x1p31);
    v.y = __double2int_rn((double)w2[(og +  4) * H_HID + h] * 0x1p31);
    v.z = __double2int_rn((double)w2[(og +  8) * H_HID + h] * 0x1p31);
    v.w = __double2int_rn((double)w2[(og + 12) * H_HID + h] * 0x1p31);
    w2a[i] = v;
    w2b[i] = __double2int_rn((double)w2[(og + 16) * H_HID + h] * 0x1p31);
  }
  __syncthreads();
  const int wv   = threadIdx.x >> 6;
  const int lane = threadIdx.x & 63;
  const int hw = lane >> 2, og = lane & 3;

  for (int t = wv; t < T_SMP; t += 8) {
    const int id = n * T_SMP + t;
    uint64_t m = s1m[(size_t)id * 16 + hw];
    long long acc0 = 0, acc1 = 0, acc2 = 0, acc3 = 0, acc4 = 0;
    while (m) {
      int b = __builtin_ctzll(m);
      m &= m - 1;
      const int h = hw * 64 + b;
      const int4 va = w2a[h * 4 + og];
      const int  vb = w2b[h * 4 + og];
      acc0 += va.x;
      acc1 += va.y;
      acc2 += va.z;
      acc3 += va.w;
      acc4 += vb;
    }
    #pragma unroll
    for (int off = 4; off <= 32; off <<= 1) {
      acc0 += __shfl_xor(acc0, off);
      acc1 += __shfl_xor(acc1, off);
      acc2 += __shfl_xor(acc2, off);
      acc3 += __shfl_xor(acc3, off);
      acc4 += __shfl_xor(acc4, off);
    }
    if (lane < 4) {
      float* ub = u2 + (size_t)t * (N_BATCH * O_OUT) + n * O_OUT + og;
      ub[0]  = (float)((double)acc0 * 0x1p-31);
      ub[4]  = (float)((double)acc1 * 0x1p-31);
      ub[8]  = (float)((double)acc2 * 0x1p-31);
      ub[12] = (float)((double)acc3 * 0x1p-31);
      ub[16] = (float)((double)acc4 * 0x1p-31);
    }
  }
}

// ---------------------------------------------------------------------------
// K4: layer-2 psp (fp64 IIR) + spike scan, write concatenated output.
// ---------------------------------------------------------------------------
__global__ void __launch_bounds__(256) k_psp_spike_out(
    const float* __restrict__ u2_m, const float* __restrict__ u2_l,
    float* __restrict__ out)
{
  const int rid = blockIdx.x * 256 + threadIdx.x;   // 0..5119
  const int p = rid / (N_BATCH * O_OUT);
  const int r = rid % (N_BATCH * O_OUT);            // n*20+o
  const float* up = (p == 0) ? u2_m : u2_l;
  float* ob = out + (size_t)r * (2 * T_SMP) + p * T_SMP;
  float pend[15];
  #pragma unroll
  for (int d = 0; d < 15; ++d) pend[d] = 0.0f;
  double e1 = 0.0, e2 = 0.0;
  for (int t = 0; t < T_SMP; ++t) {
    double xv = (double)up[(size_t)t * (N_BATCH * O_OUT) + r];
    e1 = IIR_A * e1 + xv;
    e2 = IIR_A * e2 + e1;
    float uf = (float)(IIR_CK * (e2 - e1));
    float um = uf + pend[0];
    float s  = (um >= 10.0f) ? 1.0f : 0.0f;
    #pragma unroll
    for (int d = 0; d < 14; ++d) pend[d] = fmaf(s, REFN_C[d], pend[d + 1]);
    pend[14] = s * REFN_C[14];
    ob[t] = s;
  }
}

// ---------------------------------------------------------------------------
extern "C" void kernel_launch(void* const* d_in, const int* in_sizes, int n_in,
                              void* d_out, int out_size, void* d_ws, size_t ws_size,
                              hipStream_t stream) {
  const float* x      = (const float*)d_in[0];
  const float* w_fc1  = (const float*)d_in[1];
  const float* w_fc2  = (const float*)d_in[2];
  const float* w_loc1 = (const float*)d_in[3];
  const float* w_loc2 = (const float*)d_in[4];
  float* out = (float*)d_out;
  char* ws = (char*)d_ws;

  // workspace layout
  uint32_t* lists_m = (uint32_t*)(ws + 0);          //  3,194,880
  uint32_t* lists_l = (uint32_t*)(ws + 3194880);    //  3,194,880
  uint32_t* cnt_m   = (uint32_t*)(ws + 6389760);    //     79,872
  uint32_t* cnt_l   = (uint32_t*)(ws + 6469632);    //     79,872
  uint64_t* s1m_m   = (uint64_t*)(ws + 6549504);    //  2,555,904
  uint64_t* s1m_l   = (uint64_t*)(ws + 9105408);    //  2,555,904
  float*    u2_m    = (float*)   (ws + 11661312);   //  1,597,440
  float*    u2_l    = (float*)   (ws + 13258752);   //  1,597,440

  hipLaunchKernelGGL(k_build_lists, dim3(128), dim3(256),
                     C_IN * T_SMP * sizeof(float), stream,
                     x, lists_m, cnt_m, lists_l, cnt_l);
  hipLaunchKernelGGL(k_layer1, dim3(16, 32, 2), dim3(256),
                     157 * 64 * sizeof(uint32_t), stream,
                     w_fc1, w_loc1, lists_m, cnt_m, lists_l, cnt_l, s1m_m, s1m_l);
  hipLaunchKernelGGL(k_layer2, dim3(128, 2), dim3(512),
                     H_HID * 4 * sizeof(int4) + H_HID * 4 * sizeof(int), stream,
                     w_fc2, w_loc2, s1m_m, s1m_l, u2_m, u2_l);
  hipLaunchKernelGGL(k_psp_spike_out, dim3(20), dim3(256), 0, stream,
                     u2_m, u2_l, out);
}